// Round 5
// baseline (3439.224 us; speedup 1.0000x reference)
//
#include <hip/hip_runtime.h>

typedef __attribute__((ext_vector_type(8))) _Float16 v8h;
typedef __attribute__((ext_vector_type(4))) float v4f;

#define DEV __device__ __forceinline__

constexpr int S_ = 64;
constexpr int B_ = 256;
constexpr int E_ = 131072;
constexpr int T_ = S_ * B_;   // 16384

DEV float sigm(float x) { return 1.f / (1.f + __expf(-x)); }
DEV float tanh_f(float x) { return 1.f - 2.f / (__expf(2.f * x) + 1.f); }

// ---------------- weight fp32 -> fp16 (hi, optional lo residual) ----------------
struct CJob { const float* s; _Float16* d; _Float16* dlo; int n; int rowLen; int stride; };
struct CJobs { CJob j[9]; };

__global__ __launch_bounds__(256) void convert_k(CJobs jobs) {
  for (int q = 0; q < 9; ++q) {
    CJob jb = jobs.j[q];
    for (int i = blockIdx.x * 256 + threadIdx.x; i < jb.n; i += gridDim.x * 256) {
      int row = i / jb.rowLen;
      int col = i - row * jb.rowLen;
      float f = jb.s[(long)row * jb.stride + col];
      _Float16 hi = (_Float16)f;
      jb.d[i] = hi;
      if (jb.dlo) jb.dlo[i] = (_Float16)(f - (float)hi);
    }
  }
}

// ---------------- node embedding gather (fp32 table -> fp32) ----------------
__global__ __launch_bounds__(256) void embed_k(const int* __restrict__ nt,
                                               const float* __restrict__ tab,
                                               float* __restrict__ x0) {
  int t = blockIdx.x, j = threadIdx.x;
  x0[(long)t * 256 + j] = tab[nt[t] * 256 + j];
}

// ---------------- per-edge-type bias: pe[16][256] = edge_table @ W_e^T + bmsg (fp32 exact) ----------------
__global__ __launch_bounds__(256) void pe_k(const float* __restrict__ etab,
                                            const float* __restrict__ Wmsg,
                                            const float* __restrict__ bmsg,
                                            float* __restrict__ pe) {
  int j = threadIdx.x;
  const float* w = Wmsg + (long)j * 512 + 256;  // W_e = Wmsg[:, 256:512]
  for (int r = 0; r < 16; ++r) {
    float acc = bmsg[j];
    const float* e = etab + r * 256;
    for (int k = 0; k < 256; ++k) acc += e[k] * w[k];
    pe[r * 256 + j] = acc;
  }
}

// ---------------- CSR build (by dst) ----------------
__global__ __launch_bounds__(256) void count_k(const int* __restrict__ dst, int* __restrict__ cnt) {
  int e = blockIdx.x * 256 + threadIdx.x;
  if (e < E_) atomicAdd(&cnt[dst[e]], 1);
}

__global__ __launch_bounds__(256) void csr_scan_k(const int* __restrict__ cnt,
                                                  int* __restrict__ rowptr,
                                                  int* __restrict__ cur) {
  __shared__ int ps[256];
  int tid = threadIdx.x;
  int base = tid * 64;
  int s = 0;
  for (int i = 0; i < 64; ++i) s += cnt[base + i];
  ps[tid] = s;
  __syncthreads();
  for (int d = 1; d < 256; d <<= 1) {
    int v = (tid >= d) ? ps[tid - d] : 0;
    __syncthreads();
    ps[tid] += v;
    __syncthreads();
  }
  int run = (tid == 0) ? 0 : ps[tid - 1];
  for (int i = 0; i < 64; ++i) {
    rowptr[base + i] = run;
    cur[base + i] = run;
    run += cnt[base + i];
  }
  if (tid == 255) rowptr[T_] = run;
}

__global__ __launch_bounds__(256) void fill_k(const int* __restrict__ dst,
                                              int* __restrict__ cur,
                                              int* __restrict__ eord) {
  int e = blockIdx.x * 256 + threadIdx.x;
  if (e < E_) {
    int p = atomicAdd(&cur[dst[e]], 1);
    eord[p] = e;
  }
}

// ---------------- MFMA GEMM: C[M,N] = A[M,K]_fp32 @ W[N,K]^T (+bias) ----------------
// A split on the fly into fp16 hi+lo; W fp16 hi (+lo if WLO).
// 3-term: a_hi*w_hi + a_lo*w_hi + a_hi*w_lo  ->  ~fp32-equivalent.
template <int WLO, int C32, int BIAS>
__global__ __launch_bounds__(256) void gemm_nt(const float* __restrict__ Ap,
                                               const _Float16* __restrict__ Wp,
                                               const _Float16* __restrict__ Wlp,
                                               const float* __restrict__ bias,
                                               void* __restrict__ Cp,
                                               int M, int N, int K,
                                               long sA, long sW, long sB, long sC) {
  __shared__ _Float16 As[64][40];
  __shared__ _Float16 Al[64][40];
  __shared__ _Float16 Bs[64][40];
  __shared__ _Float16 Bl[64][40];
  const int bz = blockIdx.z;
  const int m0 = blockIdx.x * 64, n0 = blockIdx.y * 64;
  const int tid = threadIdx.x, lane = tid & 63, wv = tid >> 6;
  const int wy = wv >> 1, wx = wv & 1;
  const int sr = tid >> 2, skc = tid & 3;
  const _Float16* W = Wp + bz * sW;
  const float* A = Ap + bz * sA;
  v4f z4 = {0.f, 0.f, 0.f, 0.f};
  v4f acc[2][2];
  acc[0][0] = z4; acc[0][1] = z4; acc[1][0] = z4; acc[1][1] = z4;

  for (int k0 = 0; k0 < K; k0 += 32) {
    {
      const float* p = A + (long)(m0 + sr) * K + k0 + skc * 8;
      v4f f0 = *(const v4f*)p;
      v4f f1 = *(const v4f*)(p + 4);
      v8h hv, lv;
#pragma unroll
      for (int j = 0; j < 4; ++j) {
        hv[j] = (_Float16)f0[j]; lv[j] = (_Float16)(f0[j] - (float)hv[j]);
        hv[4 + j] = (_Float16)f1[j]; lv[4 + j] = (_Float16)(f1[j] - (float)hv[4 + j]);
      }
      *(v8h*)&As[sr][skc * 8] = hv;
      *(v8h*)&Al[sr][skc * 8] = lv;
    }
    *(v8h*)&Bs[sr][skc * 8] = *(const v8h*)(W + (long)(n0 + sr) * K + k0 + skc * 8);
    if constexpr (WLO)
      *(v8h*)&Bl[sr][skc * 8] = *(const v8h*)(Wlp + bz * sW + (long)(n0 + sr) * K + k0 + skc * 8);
    __syncthreads();
    const int fr = lane & 15, fk = (lane >> 4) * 8;
    v8h ah[2], alr[2], bh[2], blr[2];
    ah[0] = *(v8h*)&As[wy * 32 + fr][fk];
    ah[1] = *(v8h*)&As[wy * 32 + 16 + fr][fk];
    bh[0] = *(v8h*)&Bs[wx * 32 + fr][fk];
    bh[1] = *(v8h*)&Bs[wx * 32 + 16 + fr][fk];
    alr[0] = *(v8h*)&Al[wy * 32 + fr][fk];
    alr[1] = *(v8h*)&Al[wy * 32 + 16 + fr][fk];
    if constexpr (WLO) {
      blr[0] = *(v8h*)&Bl[wx * 32 + fr][fk];
      blr[1] = *(v8h*)&Bl[wx * 32 + 16 + fr][fk];
    }
#pragma unroll
    for (int mi = 0; mi < 2; ++mi)
#pragma unroll
      for (int ni = 0; ni < 2; ++ni) {
        acc[mi][ni] = __builtin_amdgcn_mfma_f32_16x16x32_f16(ah[mi], bh[ni], acc[mi][ni], 0, 0, 0);
        acc[mi][ni] = __builtin_amdgcn_mfma_f32_16x16x32_f16(alr[mi], bh[ni], acc[mi][ni], 0, 0, 0);
        if constexpr (WLO)
          acc[mi][ni] = __builtin_amdgcn_mfma_f32_16x16x32_f16(ah[mi], blr[ni], acc[mi][ni], 0, 0, 0);
      }
    __syncthreads();
  }
  const int fr = lane & 15, fq = lane >> 4;
#pragma unroll
  for (int mi = 0; mi < 2; ++mi)
#pragma unroll
    for (int ni = 0; ni < 2; ++ni)
#pragma unroll
      for (int j = 0; j < 4; ++j) {
        int row = m0 + wy * 32 + mi * 16 + fq * 4 + j;
        int col = n0 + wx * 32 + ni * 16 + fr;
        float v = acc[mi][ni][j];
        if (BIAS) v += bias[bz * sB + col];
        if (C32)
          ((float*)Cp)[bz * sC + (long)row * N + col] = v;
        else
          ((_Float16*)Cp)[bz * sC + (long)row * N + col] = (_Float16)v;
      }
}

// ---------------- recurrent GRU layer: WEIGHT-RESIDENT, LDS = 112KB ----------------
// Block = 16 batch rows x 1 direction, 256 threads (4 waves).
// Whh r,z gates (own 64-col slice) + n-gate ht=3 tile -> per-wave REGISTERS;
// n-gate ht-tiles 0..2 (192 cols) -> LDS (96KB). Weights are step-invariant.
// h fp32 in regs; fp16 hi+lo single buffer in LDS, 2 barriers/step.
__global__ __launch_bounds__(256, 1) void gru_layer_k(const float* __restrict__ gi,      // (2,T,768) fp32, bih included
                                                      const _Float16* __restrict__ Whh,  // (2,768,256) fp16
                                                      const float* __restrict__ bhh,     // (2,768)
                                                      float* __restrict__ y,             // (T,512) fp32
                                                      float* __restrict__ hfinal) {      // (2,256,256) fp32
  __shared__ _Float16 wlds[49152];  // 96KB: n-gate ht<3, [kch][w][ht][col16][8]
  __shared__ _Float16 hbh[4096];    // 8KB: h hi, [kc][fq][row][8]
  __shared__ _Float16 hbl[4096];    // 8KB: h lo
  const int dir = blockIdx.y;
  const int r0 = blockIdx.x * 16;
  const int tid = threadIdx.x, lane = tid & 63, w = tid >> 6;
  const int fr = lane & 15, fq = lane >> 4;
  const _Float16* Wd = Whh + (long)dir * 768 * 256;
  const float* gid = gi + (long)dir * T_ * 768;

  // stage n-gate ht-tiles 0..2 into LDS: i = ((kch*4 + w)*3 + ht)*16 + c16
  for (int i = tid; i < 6144; i += 256) {
    int c16 = i & 15;
    int r = i >> 4;
    int ht = r % 3; r /= 3;
    int wq = r & 3;
    int kch = r >> 2;
    int col = wq * 64 + ht * 16 + c16;
    *(v8h*)&wlds[(size_t)i * 8] = *(const v8h*)(Wd + (long)(512 + col) * 256 + kch * 8);
  }
  // zero h
  for (int i = tid; i < 2048; i += 256) { ((int*)hbh)[i] = 0; ((int*)hbl)[i] = 0; }

  // r,z weights + n ht=3 tile -> registers (read-only across the step loop)
  v8h wr0[4][8], wr1[4][8], wn3[8];
#pragma unroll
  for (int ht = 0; ht < 4; ++ht)
#pragma unroll
    for (int kc = 0; kc < 8; ++kc) {
      wr0[ht][kc] = *(const v8h*)(Wd + (long)(w * 64 + ht * 16 + fr) * 256 + kc * 32 + fq * 8);
      wr1[ht][kc] = *(const v8h*)(Wd + (long)(256 + w * 64 + ht * 16 + fr) * 256 + kc * 32 + fq * 8);
    }
#pragma unroll
  for (int kc = 0; kc < 8; ++kc)
    wn3[kc] = *(const v8h*)(Wd + (long)(512 + w * 64 + 48 + fr) * 256 + kc * 32 + fq * 8);

  float bhv[3][4];
#pragma unroll
  for (int g = 0; g < 3; ++g)
#pragma unroll
    for (int ht = 0; ht < 4; ++ht)
      bhv[g][ht] = bhh[(long)dir * 768 + g * 256 + w * 64 + ht * 16 + fr];

  float hreg[4][4];
#pragma unroll
  for (int a = 0; a < 4; ++a)
#pragma unroll
    for (int b = 0; b < 4; ++b) hreg[a][b] = 0.f;
  __syncthreads();

  const v4f z4 = {0.f, 0.f, 0.f, 0.f};
  for (int step = 0; step < 64; ++step) {
    const int t = dir ? 63 - step : step;
    const float* rowp = gid + ((long)t * 256 + r0 + fq * 4) * 768 + w * 64 + fr;
    // read h fragments (prev step): a[kc][j] = h[row=fr][k = kc*32 + fq*8 + j]
    v8h a[8], al[8];
#pragma unroll
    for (int kc = 0; kc < 8; ++kc) {
      a[kc] = *(const v8h*)&hbh[((kc * 4 + fq) * 16 + fr) * 8];
      al[kc] = *(const v8h*)&hbl[((kc * 4 + fq) * 16 + fr) * 8];
    }
    __syncthreads();  // all reads done before any write

    float gc[12], gn[12];
#pragma unroll
    for (int g = 0; g < 3; ++g)
#pragma unroll
      for (int j = 0; j < 4; ++j) gc[g * 4 + j] = rowp[j * 768 + g * 256];

#pragma unroll
    for (int ht = 0; ht < 4; ++ht) {
      if (ht < 3) {
#pragma unroll
        for (int g = 0; g < 3; ++g)
#pragma unroll
          for (int j = 0; j < 4; ++j) gn[g * 4 + j] = rowp[j * 768 + g * 256 + (ht + 1) * 16];
      }
      // 6 independent MFMA chains of 8 (r/z/n-ht3 from regs, n-ht<3 from LDS)
      v4f c0h = z4, c0l = z4, c1h = z4, c1l = z4, c2h = z4, c2l = z4;
#pragma unroll
      for (int kc = 0; kc < 8; ++kc) {
        v8h w2 = (ht < 3) ? *(const v8h*)&wlds[((((kc * 4 + fq) * 4 + w) * 3 + ht) * 16 + fr) * 8]
                          : wn3[kc];
        c0h = __builtin_amdgcn_mfma_f32_16x16x32_f16(a[kc], wr0[ht][kc], c0h, 0, 0, 0);
        c0l = __builtin_amdgcn_mfma_f32_16x16x32_f16(al[kc], wr0[ht][kc], c0l, 0, 0, 0);
        c1h = __builtin_amdgcn_mfma_f32_16x16x32_f16(a[kc], wr1[ht][kc], c1h, 0, 0, 0);
        c1l = __builtin_amdgcn_mfma_f32_16x16x32_f16(al[kc], wr1[ht][kc], c1l, 0, 0, 0);
        c2h = __builtin_amdgcn_mfma_f32_16x16x32_f16(a[kc], w2, c2h, 0, 0, 0);
        c2l = __builtin_amdgcn_mfma_f32_16x16x32_f16(al[kc], w2, c2l, 0, 0, 0);
      }
      v4f ar = c0h + c0l, az = c1h + c1l, an = c2h + c2l;
#pragma unroll
      for (int j = 0; j < 4; ++j) {
        float rr = sigm(gc[j] + ar[j] + bhv[0][ht]);
        float zz = sigm(gc[4 + j] + az[j] + bhv[1][ht]);
        float nn = tanh_f(gc[8 + j] + rr * (an[j] + bhv[2][ht]));
        float hnew = (1.f - zz) * nn + zz * hreg[ht][j];
        hreg[ht][j] = hnew;
        y[((long)t * 256 + r0 + fq * 4 + j) * 512 + (long)dir * 256 + w * 64 + ht * 16 + fr] = hnew;
        _Float16 hv = (_Float16)hnew;
        // store h[row=fq*4+j][col=w*64+ht*16+fr] at [kc=col>>5][fqr=(col>>3)&3][row][col&7]
        int idx = (((w * 2 + (ht >> 1)) * 4 + ((ht & 1) * 2 + (fr >> 3))) * 16 + (fq * 4 + j)) * 8 + (fr & 7);
        hbh[idx] = hv;
        hbl[idx] = (_Float16)(hnew - (float)hv);
      }
      if (ht < 3) {
#pragma unroll
        for (int q = 0; q < 12; ++q) gc[q] = gn[q];
      }
    }
    __syncthreads();  // writes visible before next step's reads
  }
#pragma unroll
  for (int ht = 0; ht < 4; ++ht)
#pragma unroll
    for (int j = 0; j < 4; ++j)
      hfinal[((long)dir * 256 + r0 + fq * 4 + j) * 256 + w * 64 + ht * 16 + fr] = hreg[ht][j];
}

// ---------------- seq-major -> node-major permutation (fp32 rows of 512) ----------------
__global__ __launch_bounds__(256) void permgather_k(const float* __restrict__ inp, float* __restrict__ nb) {
  int t = blockIdx.x, tid = threadIdx.x;
  const float* s = inp + ((long)(t & 63) * 256 + (t >> 6)) * 512;
  float* d = nb + (long)t * 512;
  d[tid] = s[tid];
  d[tid + 256] = s[tid + 256];
}

// ---------------- CSR aggregation: agg[v] = sum_{e: dst=v} P[src[e]] + pe[et[e]] ----------------
__global__ __launch_bounds__(256) void aggregate_k(const int* __restrict__ rowptr,
                                                   const int* __restrict__ eord,
                                                   const int* __restrict__ src,
                                                   const int* __restrict__ et,
                                                   const float* __restrict__ P,
                                                   const float* __restrict__ pe,
                                                   float* __restrict__ agg) {
  int v = blockIdx.x * 4 + (threadIdx.x >> 6);
  int lane = threadIdx.x & 63;
  int b0 = rowptr[v], b1 = rowptr[v + 1];
  v4f acc = {0.f, 0.f, 0.f, 0.f};
  for (int i = b0; i < b1; ++i) {
    int e = eord[i];
    int s = src[e], ty = et[e];
    v4f pv = *(const v4f*)(P + (long)s * 256 + lane * 4);
    v4f ev = *(const v4f*)(pe + ty * 256 + lane * 4);
    acc += pv + ev;
  }
  *(v4f*)(agg + (long)v * 256 + lane * 4) = acc;
}

// ---------------- GRU cell elementwise (biases already in gi2/gh2) ----------------
__global__ __launch_bounds__(256) void cell_ew_k(const float* __restrict__ gi2,
                                                 const float* __restrict__ gh2,
                                                 float* __restrict__ nodeh) {
  int node = blockIdx.x, j = threadIdx.x;
  const float* a = gi2 + (long)node * 768;
  const float* b = gh2 + (long)node * 768;
  float rr = sigm(a[j] + b[j]);
  float zz = sigm(a[j + 256] + b[j + 256]);
  float nn = tanh_f(a[j + 512] + rr * b[j + 512]);
  float h = nodeh[(long)node * 256 + j];
  nodeh[(long)node * 256 + j] = (1.f - zz) * nn + zz * h;
}

// ---------------- gated sum per graph (fp32 pre-activations) ----------------
__global__ __launch_bounds__(256) void graph_reduce_k(const float* __restrict__ gt,
                                                      const float* __restrict__ bgate,
                                                      const float* __restrict__ bemb,
                                                      float* __restrict__ ge) {
  int g = blockIdx.x, tid = threadIdx.x;
  for (int col = tid; col < 512; col += 256) {
    float bg = bgate[col], be = bemb[col];
    float acc = 0.f;
    for (int p = 0; p < 64; ++p) {
      const float* row = gt + ((long)g * 64 + p) * 1024;
      acc += sigm(row[col] + bg) * (row[512 + col] + be);
    }
    ge[(long)g * 512 + col] = acc;
  }
}

// ---------------- merged = [hf|hb|graph_emb] @ Wglob^T + bglob (fp32) ----------------
__global__ __launch_bounds__(256) void merged_k(const float* __restrict__ hfinal,
                                                const float* __restrict__ ge,
                                                const float* __restrict__ Wglob,
                                                const float* __restrict__ bglob,
                                                float* __restrict__ out) {
  __shared__ float vec[1024];
  int g = blockIdx.x, tid = threadIdx.x;
  vec[tid] = hfinal[(long)g * 256 + tid];
  vec[256 + tid] = hfinal[(long)65536 + g * 256 + tid];
  vec[512 + tid] = ge[(long)g * 512 + tid];
  vec[768 + tid] = ge[(long)g * 512 + 256 + tid];
  __syncthreads();
  const float* wr = Wglob + (long)tid * 1024;
  float acc = bglob[tid];
  for (int k = 0; k < 1024; ++k) acc += vec[k] * wr[k];
  out[(long)g * 256 + tid] = acc;
}

// =========================== host ===========================
extern "C" void kernel_launch(void* const* d_in, const int* in_sizes, int n_in,
                              void* d_out, int out_size, void* d_ws, size_t ws_size,
                              hipStream_t stream) {
  (void)in_sizes; (void)n_in; (void)out_size; (void)ws_size;
  const float* node_table = (const float*)d_in[0];
  const float* Wih_l0 = (const float*)d_in[1];
  const float* Wih_l12 = (const float*)d_in[2];
  const float* WhhF = (const float*)d_in[3];
  const float* bih = (const float*)d_in[4];
  const float* bhh = (const float*)d_in[5];
  const float* WmdF = (const float*)d_in[6];
  const float* bmd = (const float*)d_in[7];
  const float* edge_table = (const float*)d_in[8];
  const float* Wmsg = (const float*)d_in[9];
  const float* bmsg = (const float*)d_in[10];
  const float* cWih = (const float*)d_in[11];
  const float* cWhh = (const float*)d_in[12];
  const float* cbih = (const float*)d_in[13];
  const float* cbhh = (const float*)d_in[14];
  const float* Wgate = (const float*)d_in[15];
  const float* bgate = (const float*)d_in[16];
  const float* Wemb = (const float*)d_in[17];
  const float* bemb = (const float*)d_in[18];
  const float* Wglob = (const float*)d_in[19];
  const float* bglob = (const float*)d_in[20];
  const int* node_types = (const int*)d_in[21];
  const int* edge_types = (const int*)d_in[22];
  const int* srcI = (const int*)d_in[23];
  const int* dstI = (const int*)d_in[24];

  float* node_h = (float*)d_out;                  // (T,256) = output 0, used as working buffer
  float* merged = (float*)d_out + (long)T_ * 256; // (256,256) = output 1

  char* w = (char*)d_ws;
  size_t off = 0;
  auto alloc = [&](size_t bytes) -> char* {
    char* ptr = w + off;
    off = (off + bytes + 255) & ~(size_t)255;
    return ptr;
  };
  _Float16* wWih0H = (_Float16*)alloc((size_t)2 * 768 * 256 * 2);
  _Float16* wWih0L = (_Float16*)alloc((size_t)2 * 768 * 256 * 2);
  _Float16* wWih12H = (_Float16*)alloc((size_t)2 * 2 * 768 * 512 * 2);
  _Float16* wWih12L = (_Float16*)alloc((size_t)2 * 2 * 768 * 512 * 2);
  _Float16* wWhh = (_Float16*)alloc((size_t)3 * 2 * 768 * 256 * 2);
  _Float16* wWmdH = (_Float16*)alloc((size_t)256 * 512 * 2);
  _Float16* wWmdL = (_Float16*)alloc((size_t)256 * 512 * 2);
  _Float16* wWxH = (_Float16*)alloc((size_t)256 * 256 * 2);
  _Float16* wWxL = (_Float16*)alloc((size_t)256 * 256 * 2);
  _Float16* wCWihH = (_Float16*)alloc((size_t)768 * 256 * 2);
  _Float16* wCWihL = (_Float16*)alloc((size_t)768 * 256 * 2);
  _Float16* wCWhhH = (_Float16*)alloc((size_t)768 * 256 * 2);
  _Float16* wCWhhL = (_Float16*)alloc((size_t)768 * 256 * 2);
  _Float16* wWcatH = (_Float16*)alloc((size_t)1024 * 256 * 2);
  _Float16* wWcatL = (_Float16*)alloc((size_t)1024 * 256 * 2);
  float* inpA = (float*)alloc((size_t)T_ * 512 * 4);
  float* inpB = (float*)alloc((size_t)T_ * 512 * 4);
  float* agg = (float*)alloc((size_t)T_ * 256 * 4);
  float* hfinal = (float*)alloc((size_t)2 * 256 * 256 * 4);
  float* pe = (float*)alloc((size_t)16 * 256 * 4);
  int* cnt = (int*)alloc((size_t)T_ * 4);
  int* rowptr = (int*)alloc((size_t)(T_ + 1) * 4);
  int* cur = (int*)alloc((size_t)T_ * 4);
  int* eord = (int*)alloc((size_t)E_ * 4);
  float* gemb = (float*)alloc((size_t)256 * 512 * 4);
  // Union region, 112 MB: phases do not overlap in time.
  //   GRU phase:  gi (2,T,768) fp32 = 96 MB @ +0 ; x0 (T,256) fp32 = 16 MB @ +96M
  //   MP phase:   Pbuf (T,256) = 16 MB @ +0 ; gi2 (T,768) = 48 MB @ +16M ; gh2 @ +64M
  //   epilogue:   gated (T,1024) fp32 = 64 MB @ +0
  char* R = alloc((size_t)112 * 1024 * 1024);
  float* gi = (float*)R;
  float* x0 = (float*)(R + (size_t)96 * 1024 * 1024);
  float* Pbuf = (float*)R;
  float* gi2 = (float*)(R + (size_t)16 * 1024 * 1024);
  float* gh2 = (float*)(R + (size_t)64 * 1024 * 1024);
  float* gatedF = (float*)R;

  // 1. weights -> fp16 hi (+ lo residual where W-systematic error matters downstream)
  CJobs jobs;
  jobs.j[0] = {Wih_l0, wWih0H, wWih0L, 2 * 768 * 256, 2 * 768 * 256, 2 * 768 * 256};
  jobs.j[1] = {Wih_l12, wWih12H, wWih12L, 2 * 2 * 768 * 512, 2 * 2 * 768 * 512, 2 * 2 * 768 * 512};
  jobs.j[2] = {WhhF, wWhh, nullptr, 3 * 2 * 768 * 256, 3 * 2 * 768 * 256, 3 * 2 * 768 * 256};
  jobs.j[3] = {WmdF, wWmdH, wWmdL, 256 * 512, 256 * 512, 256 * 512};
  jobs.j[4] = {Wmsg, wWxH, wWxL, 256 * 256, 256, 512};  // W_x = Wmsg[:, :256]
  jobs.j[5] = {cWih, wCWihH, wCWihL, 768 * 256, 768 * 256, 768 * 256};
  jobs.j[6] = {cWhh, wCWhhH, wCWhhL, 768 * 256, 768 * 256, 768 * 256};
  jobs.j[7] = {Wgate, wWcatH, wWcatL, 512 * 256, 512 * 256, 512 * 256};
  jobs.j[8] = {Wemb, wWcatH + 512 * 256, wWcatL + 512 * 256, 512 * 256, 512 * 256, 512 * 256};
  convert_k<<<1024, 256, 0, stream>>>(jobs);

  // 2. embeddings, edge-type bias, CSR
  embed_k<<<T_, 256, 0, stream>>>(node_types, node_table, x0);
  pe_k<<<1, 256, 0, stream>>>(edge_table, Wmsg, bmsg, pe);
  hipMemsetAsync(cnt, 0, (size_t)T_ * 4, stream);
  count_k<<<E_ / 256, 256, 0, stream>>>(dstI, cnt);
  csr_scan_k<<<1, 256, 0, stream>>>(cnt, rowptr, cur);
  fill_k<<<E_ / 256, 256, 0, stream>>>(dstI, cur, eord);

  // 3. three bidirectional GRU layers (gi fp32 via 3-term split GEMM; weight-resident recurrence)
  const float* inCur = x0;
  float* outBuf[3] = {inpA, inpB, inpA};
  int Kin = 256;
  for (int l = 0; l < 3; ++l) {
    const _Float16 *WlH, *WlL;
    long sW;
    if (l == 0) { WlH = wWih0H; WlL = wWih0L; sW = (long)768 * 256; }
    else {
      WlH = wWih12H + (size_t)(l - 1) * 2 * 768 * 512;
      WlL = wWih12L + (size_t)(l - 1) * 2 * 768 * 512;
      sW = (long)768 * 512;
    }
    gemm_nt<1, 1, 1><<<dim3(T_ / 64, 12, 2), 256, 0, stream>>>(
        inCur, WlH, WlL, bih + (long)l * 2 * 768, gi, T_, 768, Kin, 0L, sW, 768L, (long)T_ * 768);
    gru_layer_k<<<dim3(16, 2), 256, 0, stream>>>(
        gi, wWhh + (size_t)l * 2 * 768 * 256, bhh + (long)l * 2 * 768, outBuf[l], hfinal);
    inCur = outBuf[l];
    Kin = 512;
  }

  // 4. permute seq-major -> node-major; node_h = node_bidir @ Wmd^T + bmd
  permgather_k<<<T_, 256, 0, stream>>>(inpA, inpB);
  gemm_nt<1, 1, 1><<<dim3(T_ / 64, 4, 1), 256, 0, stream>>>(
      inpB, wWmdH, wWmdL, bmd, node_h, T_, 256, 512, 0L, 0L, 0L, 0L);

  // 5. message passing x3 (3-term split GEMMs: ~fp32 precision)
  for (int it = 0; it < 3; ++it) {
    gemm_nt<1, 1, 0><<<dim3(T_ / 64, 4, 1), 256, 0, stream>>>(
        node_h, wWxH, wWxL, nullptr, Pbuf, T_, 256, 256, 0L, 0L, 0L, 0L);
    aggregate_k<<<T_ / 4, 256, 0, stream>>>(rowptr, eord, srcI, edge_types, Pbuf, pe, agg);
    gemm_nt<1, 1, 1><<<dim3(T_ / 64, 12, 1), 256, 0, stream>>>(
        agg, wCWihH, wCWihL, cbih, gi2, T_, 768, 256, 0L, 0L, 0L, 0L);
    gemm_nt<1, 1, 1><<<dim3(T_ / 64, 12, 1), 256, 0, stream>>>(
        node_h, wCWhhH, wCWhhL, cbhh, gh2, T_, 768, 256, 0L, 0L, 0L, 0L);
    cell_ew_k<<<T_, 256, 0, stream>>>(gi2, gh2, node_h);
  }

  // 6. gated projections (3-term, fp32 out) + per-graph sum + merged
  gemm_nt<1, 1, 0><<<dim3(T_ / 64, 16, 1), 256, 0, stream>>>(
      node_h, wWcatH, wWcatL, nullptr, gatedF, T_, 1024, 256, 0L, 0L, 0L, 0L);
  graph_reduce_k<<<256, 256, 0, stream>>>(gatedF, bgate, bemb, gemb);
  merged_k<<<256, 256, 0, stream>>>(hfinal, gemb, Wglob, bglob, merged);
}

// Round 7
// 2192.046 us; speedup vs baseline: 1.5690x; 1.5690x over previous
//
#include <hip/hip_runtime.h>

typedef __attribute__((ext_vector_type(8))) _Float16 v8h;
typedef __attribute__((ext_vector_type(4))) float v4f;
typedef __attribute__((ext_vector_type(4))) int i4;

#define DEV __device__ __forceinline__

constexpr int S_ = 64;
constexpr int B_ = 256;
constexpr int E_ = 131072;
constexpr int T_ = S_ * B_;   // 16384

DEV float sigm(float x) { return 1.f / (1.f + __expf(-x)); }
DEV float tanh_f(float x) { return 1.f - 2.f / (__expf(2.f * x) + 1.f); }

// MFMA with B operand pinned to AGPRs ("a" constraint) — keeps step-invariant
// weights in the AGPR file without touching the v[0:255] budget. volatile:
// preserve relative order of the accumulation chain.
DEV v4f mfma_ag(v8h a, i4 w, v4f c) {
  asm volatile("v_mfma_f32_16x16x32_f16 %0, %1, %2, %0" : "+v"(c) : "v"(a), "a"(w));
  return c;
}
// Dataflow hazard fence: the accumulator is threaded THROUGH the nops, so any
// consumer of the result is ordered after them by data dependence (the plain
// s_nop-block guard can be bypassed by scheduling — round 6's bug).
DEV v4f mfma_fence(v4f c) {
  asm volatile("s_nop 7\n\ts_nop 7" : "+v"(c));
  return c;
}

// ---------------- weight fp32 -> fp16 (hi, optional lo residual) ----------------
struct CJob { const float* s; _Float16* d; _Float16* dlo; int n; int rowLen; int stride; };
struct CJobs { CJob j[9]; };

__global__ __launch_bounds__(256) void convert_k(CJobs jobs) {
  for (int q = 0; q < 9; ++q) {
    CJob jb = jobs.j[q];
    for (int i = blockIdx.x * 256 + threadIdx.x; i < jb.n; i += gridDim.x * 256) {
      int row = i / jb.rowLen;
      int col = i - row * jb.rowLen;
      float f = jb.s[(long)row * jb.stride + col];
      _Float16 hi = (_Float16)f;
      jb.d[i] = hi;
      if (jb.dlo) jb.dlo[i] = (_Float16)(f - (float)hi);
    }
  }
}

// ---------------- node embedding gather (fp32 table -> fp16) ----------------
__global__ __launch_bounds__(256) void embed_k(const int* __restrict__ nt,
                                               const float* __restrict__ tab,
                                               _Float16* __restrict__ x0) {
  int t = blockIdx.x, j = threadIdx.x;
  x0[(long)t * 256 + j] = (_Float16)tab[nt[t] * 256 + j];
}

// ---------------- per-edge-type bias: pe[16][256] = edge_table @ W_e^T + bmsg (fp32 exact) ----------------
__global__ __launch_bounds__(256) void pe_k(const float* __restrict__ etab,
                                            const float* __restrict__ Wmsg,
                                            const float* __restrict__ bmsg,
                                            float* __restrict__ pe) {
  int j = threadIdx.x;
  const float* w = Wmsg + (long)j * 512 + 256;  // W_e = Wmsg[:, 256:512]
  for (int r = 0; r < 16; ++r) {
    float acc = bmsg[j];
    const float* e = etab + r * 256;
    for (int k = 0; k < 256; ++k) acc += e[k] * w[k];
    pe[r * 256 + j] = acc;
  }
}

// ---------------- CSR build (by dst) ----------------
__global__ __launch_bounds__(256) void count_k(const int* __restrict__ dst, int* __restrict__ cnt) {
  int e = blockIdx.x * 256 + threadIdx.x;
  if (e < E_) atomicAdd(&cnt[dst[e]], 1);
}

__global__ __launch_bounds__(256) void csr_scan_k(const int* __restrict__ cnt,
                                                  int* __restrict__ rowptr,
                                                  int* __restrict__ cur) {
  __shared__ int ps[256];
  int tid = threadIdx.x;
  int base = tid * 64;
  int s = 0;
  for (int i = 0; i < 64; ++i) s += cnt[base + i];
  ps[tid] = s;
  __syncthreads();
  for (int d = 1; d < 256; d <<= 1) {
    int v = (tid >= d) ? ps[tid - d] : 0;
    __syncthreads();
    ps[tid] += v;
    __syncthreads();
  }
  int run = (tid == 0) ? 0 : ps[tid - 1];
  for (int i = 0; i < 64; ++i) {
    rowptr[base + i] = run;
    cur[base + i] = run;
    run += cnt[base + i];
  }
  if (tid == 255) rowptr[T_] = run;
}

__global__ __launch_bounds__(256) void fill_k(const int* __restrict__ dst,
                                              int* __restrict__ cur,
                                              int* __restrict__ eord) {
  int e = blockIdx.x * 256 + threadIdx.x;
  if (e < E_) {
    int p = atomicAdd(&cur[dst[e]], 1);
    eord[p] = e;
  }
}

// ---------------- MFMA GEMM: C[M,N] = A[M,K] @ W[N,K]^T (+bias) ----------------
// AH=1: A is fp16 (plain). AH=0: A is fp32, split on the fly into fp16 hi+lo.
// WLO=1: W has a lo residual (adds a_hi*w_lo term).
template <int AH, int WLO, int C32, int BIAS>
__global__ __launch_bounds__(256) void gemm_nt(const void* __restrict__ Ap,
                                               const _Float16* __restrict__ Wp,
                                               const _Float16* __restrict__ Wlp,
                                               const float* __restrict__ bias,
                                               void* __restrict__ Cp,
                                               int M, int N, int K,
                                               long sA, long sW, long sB, long sC) {
  __shared__ _Float16 As[64][40];
  __shared__ _Float16 Al[64][40];
  __shared__ _Float16 Bs[64][40];
  __shared__ _Float16 Bl[64][40];
  const int bz = blockIdx.z;
  const int m0 = blockIdx.x * 64, n0 = blockIdx.y * 64;
  const int tid = threadIdx.x, lane = tid & 63, wv = tid >> 6;
  const int wy = wv >> 1, wx = wv & 1;
  const int sr = tid >> 2, skc = tid & 3;
  const _Float16* W = Wp + bz * sW;
  v4f z4 = {0.f, 0.f, 0.f, 0.f};
  v4f acc[2][2];
  acc[0][0] = z4; acc[0][1] = z4; acc[1][0] = z4; acc[1][1] = z4;

  for (int k0 = 0; k0 < K; k0 += 32) {
    if constexpr (AH) {
      const _Float16* A = (const _Float16*)Ap + bz * sA;
      *(v8h*)&As[sr][skc * 8] = *(const v8h*)(A + (long)(m0 + sr) * K + k0 + skc * 8);
    } else {
      const float* A = (const float*)Ap + bz * sA;
      const float* p = A + (long)(m0 + sr) * K + k0 + skc * 8;
      v4f f0 = *(const v4f*)p;
      v4f f1 = *(const v4f*)(p + 4);
      v8h hv, lv;
#pragma unroll
      for (int j = 0; j < 4; ++j) {
        hv[j] = (_Float16)f0[j]; lv[j] = (_Float16)(f0[j] - (float)hv[j]);
        hv[4 + j] = (_Float16)f1[j]; lv[4 + j] = (_Float16)(f1[j] - (float)hv[4 + j]);
      }
      *(v8h*)&As[sr][skc * 8] = hv;
      *(v8h*)&Al[sr][skc * 8] = lv;
    }
    *(v8h*)&Bs[sr][skc * 8] = *(const v8h*)(W + (long)(n0 + sr) * K + k0 + skc * 8);
    if constexpr (WLO)
      *(v8h*)&Bl[sr][skc * 8] = *(const v8h*)(Wlp + bz * sW + (long)(n0 + sr) * K + k0 + skc * 8);
    __syncthreads();
    const int fr = lane & 15, fk = (lane >> 4) * 8;
    v8h ah[2], alr[2], bh[2], blr[2];
    ah[0] = *(v8h*)&As[wy * 32 + fr][fk];
    ah[1] = *(v8h*)&As[wy * 32 + 16 + fr][fk];
    bh[0] = *(v8h*)&Bs[wx * 32 + fr][fk];
    bh[1] = *(v8h*)&Bs[wx * 32 + 16 + fr][fk];
    if constexpr (!AH) {
      alr[0] = *(v8h*)&Al[wy * 32 + fr][fk];
      alr[1] = *(v8h*)&Al[wy * 32 + 16 + fr][fk];
    }
    if constexpr (WLO) {
      blr[0] = *(v8h*)&Bl[wx * 32 + fr][fk];
      blr[1] = *(v8h*)&Bl[wx * 32 + 16 + fr][fk];
    }
#pragma unroll
    for (int mi = 0; mi < 2; ++mi)
#pragma unroll
      for (int ni = 0; ni < 2; ++ni) {
        acc[mi][ni] = __builtin_amdgcn_mfma_f32_16x16x32_f16(ah[mi], bh[ni], acc[mi][ni], 0, 0, 0);
        if constexpr (!AH)
          acc[mi][ni] = __builtin_amdgcn_mfma_f32_16x16x32_f16(alr[mi], bh[ni], acc[mi][ni], 0, 0, 0);
        if constexpr (WLO)
          acc[mi][ni] = __builtin_amdgcn_mfma_f32_16x16x32_f16(ah[mi], blr[ni], acc[mi][ni], 0, 0, 0);
      }
    __syncthreads();
  }
  const int fr = lane & 15, fq = lane >> 4;
#pragma unroll
  for (int mi = 0; mi < 2; ++mi)
#pragma unroll
    for (int ni = 0; ni < 2; ++ni)
#pragma unroll
      for (int j = 0; j < 4; ++j) {
        int row = m0 + wy * 32 + mi * 16 + fq * 4 + j;
        int col = n0 + wx * 32 + ni * 16 + fr;
        float v = acc[mi][ni][j];
        if (BIAS) v += bias[bz * sB + col];
        if (C32)
          ((float*)Cp)[bz * sC + (long)row * N + col] = v;
        else
          ((_Float16*)Cp)[bz * sC + (long)row * N + col] = (_Float16)v;
      }
}

// ---------------- recurrent GRU layer: AGPR-weight-resident ----------------
// Block = 16 batch rows x 1 dir, 4 waves. Wave w owns cols [w*64, w*64+64).
// r,z weights (64 i4 = 256 regs) -> AGPR file via asm MFMA "a" operands.
// n-gate ht0..2 -> LDS 96KB; ht3 -> VGPR. h state fp32 in regs; fp16 image
// in 8KB LDS buffer (2 barriers/step). gi fp16, all 48 loads issued up-front.
__global__ __launch_bounds__(256, 1) void gru_layer_k(const _Float16* __restrict__ gi,   // (2,T,768) fp16, bih included
                                                      const _Float16* __restrict__ Whh,  // (2,768,256) fp16
                                                      const float* __restrict__ bhh,     // (2,768)
                                                      _Float16* __restrict__ y,          // (T,512) fp16
                                                      float* __restrict__ hfinal) {      // (2,256,256) fp32
  __shared__ _Float16 wlds[49152];  // 96KB: n-gate ht<3, [kch][w][ht][col16][8]
  __shared__ _Float16 hb[4096];     // 8KB: h fp16, [kc][fq][row][8]
  const int dir = blockIdx.y;
  const int r0 = blockIdx.x * 16;
  const int tid = threadIdx.x, lane = tid & 63, w = tid >> 6;
  const int fr = lane & 15, fq = lane >> 4;
  const _Float16* Wd = Whh + (long)dir * 768 * 256;
  const _Float16* gid = gi + (long)dir * T_ * 768;

  // stage n-gate ht-tiles 0..2 into LDS: i = ((kch*4 + w)*3 + ht)*16 + c16
  for (int i = tid; i < 6144; i += 256) {
    int c16 = i & 15;
    int r = i >> 4;
    int ht = r % 3; r /= 3;
    int wq = r & 3;
    int kch = r >> 2;
    int col = wq * 64 + ht * 16 + c16;
    *(v8h*)&wlds[(size_t)i * 8] = *(const v8h*)(Wd + (long)(512 + col) * 256 + kch * 8);
  }
  for (int i = tid; i < 2048; i += 256) ((int*)hb)[i] = 0;

  // r,z weights -> AGPR-destined arrays; n ht=3 tile -> VGPR
  i4 wr[4][8], wz[4][8];
  v8h wn3[8];
#pragma unroll
  for (int ht = 0; ht < 4; ++ht)
#pragma unroll
    for (int kc = 0; kc < 8; ++kc) {
      wr[ht][kc] = *(const i4*)(Wd + (long)(w * 64 + ht * 16 + fr) * 256 + kc * 32 + fq * 8);
      wz[ht][kc] = *(const i4*)(Wd + (long)(256 + w * 64 + ht * 16 + fr) * 256 + kc * 32 + fq * 8);
    }
#pragma unroll
  for (int kc = 0; kc < 8; ++kc)
    wn3[kc] = *(const v8h*)(Wd + (long)(512 + w * 64 + 48 + fr) * 256 + kc * 32 + fq * 8);

  float bhv[3][4];
#pragma unroll
  for (int g = 0; g < 3; ++g)
#pragma unroll
    for (int ht = 0; ht < 4; ++ht)
      bhv[g][ht] = bhh[(long)dir * 768 + g * 256 + w * 64 + ht * 16 + fr];

  float hreg[4][4];
#pragma unroll
  for (int a0 = 0; a0 < 4; ++a0)
#pragma unroll
    for (int b0 = 0; b0 < 4; ++b0) hreg[a0][b0] = 0.f;
  __syncthreads();

  const v4f z4 = {0.f, 0.f, 0.f, 0.f};
  for (int step = 0; step < 64; ++step) {
    const int t = dir ? 63 - step : step;
    const _Float16* rowp = gid + ((long)t * 256 + r0 + fq * 4) * 768 + w * 64 + fr;
    // read h fragments (prev step): a[kc] = h[row=fr][k=kc*32+fq*8+0..7]
    v8h a[8];
#pragma unroll
    for (int kc = 0; kc < 8; ++kc)
      a[kc] = *(const v8h*)&hb[((kc * 4 + fq) * 16 + fr) * 8];
    // issue all 48 gi loads for this step (independent; base + imm offsets)
    float g[48];
#pragma unroll
    for (int j = 0; j < 4; ++j)
#pragma unroll
      for (int gg = 0; gg < 3; ++gg)
#pragma unroll
        for (int ht = 0; ht < 4; ++ht)
          g[(j * 3 + gg) * 4 + ht] = (float)rowp[(long)j * 768 + gg * 256 + ht * 16];
    __syncthreads();  // all h reads done before any write

#pragma unroll
    for (int ht = 0; ht < 4; ++ht) {
      v4f cr = z4, cz = z4, cn = z4;
#pragma unroll
      for (int kc = 0; kc < 8; ++kc) {
        cr = mfma_ag(a[kc], wr[ht][kc], cr);
        cz = mfma_ag(a[kc], wz[ht][kc], cz);
        v8h w2 = (ht < 3) ? *(const v8h*)&wlds[((((kc * 4 + fq) * 4 + w) * 3 + ht) * 16 + fr) * 8]
                          : wn3[kc];
        cn = __builtin_amdgcn_mfma_f32_16x16x32_f16(a[kc], w2, cn, 0, 0, 0);
      }
      cr = mfma_fence(cr);  // dataflow nop fence: VALU reads ordered after MFMA writes
      cz = mfma_fence(cz);
#pragma unroll
      for (int j = 0; j < 4; ++j) {
        float rr = sigm(g[(j * 3 + 0) * 4 + ht] + cr[j] + bhv[0][ht]);
        float zz = sigm(g[(j * 3 + 1) * 4 + ht] + cz[j] + bhv[1][ht]);
        float nn = tanh_f(g[(j * 3 + 2) * 4 + ht] + rr * (cn[j] + bhv[2][ht]));
        float hnew = (1.f - zz) * nn + zz * hreg[ht][j];
        hreg[ht][j] = hnew;
        y[((long)t * 256 + r0 + fq * 4 + j) * 512 + (long)dir * 256 + w * 64 + ht * 16 + fr] = (_Float16)hnew;
        int col = w * 64 + ht * 16 + fr;
        hb[(((col >> 5) * 4 + ((col >> 3) & 3)) * 16 + (fq * 4 + j)) * 8 + (col & 7)] = (_Float16)hnew;
      }
    }
    __syncthreads();  // writes visible before next step's reads
  }
#pragma unroll
  for (int ht = 0; ht < 4; ++ht)
#pragma unroll
    for (int j = 0; j < 4; ++j)
      hfinal[((long)dir * 256 + r0 + fq * 4 + j) * 256 + w * 64 + ht * 16 + fr] = hreg[ht][j];
}

// ---------------- seq-major -> node-major permutation (fp16 rows of 512) ----------------
__global__ __launch_bounds__(256) void permgather_k(const _Float16* __restrict__ inp, _Float16* __restrict__ nb) {
  int t = blockIdx.x, tid = threadIdx.x;
  const unsigned* s = (const unsigned*)(inp + ((long)(t & 63) * 256 + (t >> 6)) * 512);
  unsigned* d = (unsigned*)(nb + (long)t * 512);
  d[tid] = s[tid];
}

// ---------------- CSR aggregation: agg[v] = sum_{e: dst=v} P[src[e]] + pe[et[e]] ----------------
__global__ __launch_bounds__(256) void aggregate_k(const int* __restrict__ rowptr,
                                                   const int* __restrict__ eord,
                                                   const int* __restrict__ src,
                                                   const int* __restrict__ et,
                                                   const float* __restrict__ P,
                                                   const float* __restrict__ pe,
                                                   float* __restrict__ agg) {
  int v = blockIdx.x * 4 + (threadIdx.x >> 6);
  int lane = threadIdx.x & 63;
  int b0 = rowptr[v], b1 = rowptr[v + 1];
  v4f acc = {0.f, 0.f, 0.f, 0.f};
  for (int i = b0; i < b1; ++i) {
    int e = eord[i];
    int s = src[e], ty = et[e];
    v4f pv = *(const v4f*)(P + (long)s * 256 + lane * 4);
    v4f ev = *(const v4f*)(pe + ty * 256 + lane * 4);
    acc += pv + ev;
  }
  *(v4f*)(agg + (long)v * 256 + lane * 4) = acc;
}

// ---------------- GRU cell elementwise (biases already in gi2/gh2) ----------------
__global__ __launch_bounds__(256) void cell_ew_k(const float* __restrict__ gi2,
                                                 const float* __restrict__ gh2,
                                                 float* __restrict__ nodeh) {
  int node = blockIdx.x, j = threadIdx.x;
  const float* a = gi2 + (long)node * 768;
  const float* b = gh2 + (long)node * 768;
  float rr = sigm(a[j] + b[j]);
  float zz = sigm(a[j + 256] + b[j + 256]);
  float nn = tanh_f(a[j + 512] + rr * b[j + 512]);
  float h = nodeh[(long)node * 256 + j];
  nodeh[(long)node * 256 + j] = (1.f - zz) * nn + zz * h;
}

// ---------------- gated sum per graph (fp32 pre-activations) ----------------
__global__ __launch_bounds__(256) void graph_reduce_k(const float* __restrict__ gt,
                                                      const float* __restrict__ bgate,
                                                      const float* __restrict__ bemb,
                                                      float* __restrict__ ge) {
  int g = blockIdx.x, tid = threadIdx.x;
  for (int col = tid; col < 512; col += 256) {
    float bg = bgate[col], be = bemb[col];
    float acc = 0.f;
    for (int p = 0; p < 64; ++p) {
      const float* row = gt + ((long)g * 64 + p) * 1024;
      acc += sigm(row[col] + bg) * (row[512 + col] + be);
    }
    ge[(long)g * 512 + col] = acc;
  }
}

// ---------------- merged = [hf|hb|graph_emb] @ Wglob^T + bglob (fp32) ----------------
__global__ __launch_bounds__(256) void merged_k(const float* __restrict__ hfinal,
                                                const float* __restrict__ ge,
                                                const float* __restrict__ Wglob,
                                                const float* __restrict__ bglob,
                                                float* __restrict__ out) {
  __shared__ float vec[1024];
  int g = blockIdx.x, tid = threadIdx.x;
  vec[tid] = hfinal[(long)g * 256 + tid];
  vec[256 + tid] = hfinal[(long)65536 + g * 256 + tid];
  vec[512 + tid] = ge[(long)g * 512 + tid];
  vec[768 + tid] = ge[(long)g * 512 + 256 + tid];
  __syncthreads();
  const float* wr = Wglob + (long)tid * 1024;
  float acc = bglob[tid];
  for (int k = 0; k < 1024; ++k) acc += vec[k] * wr[k];
  out[(long)g * 256 + tid] = acc;
}

// =========================== host ===========================
extern "C" void kernel_launch(void* const* d_in, const int* in_sizes, int n_in,
                              void* d_out, int out_size, void* d_ws, size_t ws_size,
                              hipStream_t stream) {
  (void)in_sizes; (void)n_in; (void)out_size; (void)ws_size;
  const float* node_table = (const float*)d_in[0];
  const float* Wih_l0 = (const float*)d_in[1];
  const float* Wih_l12 = (const float*)d_in[2];
  const float* WhhF = (const float*)d_in[3];
  const float* bih = (const float*)d_in[4];
  const float* bhh = (const float*)d_in[5];
  const float* WmdF = (const float*)d_in[6];
  const float* bmd = (const float*)d_in[7];
  const float* edge_table = (const float*)d_in[8];
  const float* Wmsg = (const float*)d_in[9];
  const float* bmsg = (const float*)d_in[10];
  const float* cWih = (const float*)d_in[11];
  const float* cWhh = (const float*)d_in[12];
  const float* cbih = (const float*)d_in[13];
  const float* cbhh = (const float*)d_in[14];
  const float* Wgate = (const float*)d_in[15];
  const float* bgate = (const float*)d_in[16];
  const float* Wemb = (const float*)d_in[17];
  const float* bemb = (const float*)d_in[18];
  const float* Wglob = (const float*)d_in[19];
  const float* bglob = (const float*)d_in[20];
  const int* node_types = (const int*)d_in[21];
  const int* edge_types = (const int*)d_in[22];
  const int* srcI = (const int*)d_in[23];
  const int* dstI = (const int*)d_in[24];

  float* node_h = (float*)d_out;                  // (T,256) = output 0, used as working buffer
  float* merged = (float*)d_out + (long)T_ * 256; // (256,256) = output 1

  char* w = (char*)d_ws;
  size_t off = 0;
  auto alloc = [&](size_t bytes) -> char* {
    char* ptr = w + off;
    off = (off + bytes + 255) & ~(size_t)255;
    return ptr;
  };
  _Float16* wWih0H = (_Float16*)alloc((size_t)2 * 768 * 256 * 2);
  _Float16* wWih0L = (_Float16*)alloc((size_t)2 * 768 * 256 * 2);
  _Float16* wWih12H = (_Float16*)alloc((size_t)2 * 2 * 768 * 512 * 2);
  _Float16* wWih12L = (_Float16*)alloc((size_t)2 * 2 * 768 * 512 * 2);
  _Float16* wWhh = (_Float16*)alloc((size_t)3 * 2 * 768 * 256 * 2);
  _Float16* wWmdH = (_Float16*)alloc((size_t)256 * 512 * 2);
  _Float16* wWmdL = (_Float16*)alloc((size_t)256 * 512 * 2);
  _Float16* wWxH = (_Float16*)alloc((size_t)256 * 256 * 2);
  _Float16* wWxL = (_Float16*)alloc((size_t)256 * 256 * 2);
  _Float16* wCWihH = (_Float16*)alloc((size_t)768 * 256 * 2);
  _Float16* wCWihL = (_Float16*)alloc((size_t)768 * 256 * 2);
  _Float16* wCWhhH = (_Float16*)alloc((size_t)768 * 256 * 2);
  _Float16* wCWhhL = (_Float16*)alloc((size_t)768 * 256 * 2);
  _Float16* wWcatH = (_Float16*)alloc((size_t)1024 * 256 * 2);
  _Float16* wWcatL = (_Float16*)alloc((size_t)1024 * 256 * 2);
  _Float16* inpA = (_Float16*)alloc((size_t)T_ * 512 * 2);
  _Float16* inpB = (_Float16*)alloc((size_t)T_ * 512 * 2);
  float* agg = (float*)alloc((size_t)T_ * 256 * 4);
  float* hfinal = (float*)alloc((size_t)2 * 256 * 256 * 4);
  float* pe = (float*)alloc((size_t)16 * 256 * 4);
  int* cnt = (int*)alloc((size_t)T_ * 4);
  int* rowptr = (int*)alloc((size_t)(T_ + 1) * 4);
  int* cur = (int*)alloc((size_t)T_ * 4);
  int* eord = (int*)alloc((size_t)E_ * 4);
  float* gemb = (float*)alloc((size_t)256 * 512 * 4);
  // Union region, 112 MB: phases do not overlap in time.
  //   GRU phase:  gi (2,T,768) fp16 = 48 MB @ +0 ; x0 (T,256) fp16 = 8 MB @ +96M
  //   MP phase:   Pbuf (T,256) = 16 MB @ +0 ; gi2 (T,768) = 48 MB @ +16M ; gh2 @ +64M
  //   epilogue:   gated (T,1024) fp32 = 64 MB @ +0
  char* R = alloc((size_t)112 * 1024 * 1024);
  _Float16* gi = (_Float16*)R;
  _Float16* x0 = (_Float16*)(R + (size_t)96 * 1024 * 1024);
  float* Pbuf = (float*)R;
  float* gi2 = (float*)(R + (size_t)16 * 1024 * 1024);
  float* gh2 = (float*)(R + (size_t)64 * 1024 * 1024);
  float* gatedF = (float*)R;

  // 1. weights -> fp16 hi (+ lo residual where W-systematic error matters downstream)
  CJobs jobs;
  jobs.j[0] = {Wih_l0, wWih0H, wWih0L, 2 * 768 * 256, 2 * 768 * 256, 2 * 768 * 256};
  jobs.j[1] = {Wih_l12, wWih12H, wWih12L, 2 * 2 * 768 * 512, 2 * 2 * 768 * 512, 2 * 2 * 768 * 512};
  jobs.j[2] = {WhhF, wWhh, nullptr, 3 * 2 * 768 * 256, 3 * 2 * 768 * 256, 3 * 2 * 768 * 256};
  jobs.j[3] = {WmdF, wWmdH, wWmdL, 256 * 512, 256 * 512, 256 * 512};
  jobs.j[4] = {Wmsg, wWxH, wWxL, 256 * 256, 256, 512};  // W_x = Wmsg[:, :256]
  jobs.j[5] = {cWih, wCWihH, wCWihL, 768 * 256, 768 * 256, 768 * 256};
  jobs.j[6] = {cWhh, wCWhhH, wCWhhL, 768 * 256, 768 * 256, 768 * 256};
  jobs.j[7] = {Wgate, wWcatH, wWcatL, 512 * 256, 512 * 256, 512 * 256};
  jobs.j[8] = {Wemb, wWcatH + 512 * 256, wWcatL + 512 * 256, 512 * 256, 512 * 256, 512 * 256};
  convert_k<<<1024, 256, 0, stream>>>(jobs);

  // 2. embeddings, edge-type bias, CSR
  embed_k<<<T_, 256, 0, stream>>>(node_types, node_table, x0);
  pe_k<<<1, 256, 0, stream>>>(edge_table, Wmsg, bmsg, pe);
  hipMemsetAsync(cnt, 0, (size_t)T_ * 4, stream);
  count_k<<<E_ / 256, 256, 0, stream>>>(dstI, cnt);
  csr_scan_k<<<1, 256, 0, stream>>>(cnt, rowptr, cur);
  fill_k<<<E_ / 256, 256, 0, stream>>>(dstI, cur, eord);

  // 3. three bidirectional GRU layers (gi fp16 2-term GEMM; AGPR-resident recurrence)
  const _Float16* inCur = x0;
  _Float16* outBuf[3] = {inpA, inpB, inpA};
  int Kin = 256;
  for (int l = 0; l < 3; ++l) {
    const _Float16 *WlH, *WlL;
    long sW;
    if (l == 0) { WlH = wWih0H; WlL = wWih0L; sW = (long)768 * 256; }
    else {
      WlH = wWih12H + (size_t)(l - 1) * 2 * 768 * 512;
      WlL = wWih12L + (size_t)(l - 1) * 2 * 768 * 512;
      sW = (long)768 * 512;
    }
    gemm_nt<1, 1, 0, 1><<<dim3(T_ / 64, 12, 2), 256, 0, stream>>>(
        inCur, WlH, WlL, bih + (long)l * 2 * 768, gi, T_, 768, Kin, 0L, sW, 768L, (long)T_ * 768);
    gru_layer_k<<<dim3(16, 2), 256, 0, stream>>>(
        gi, wWhh + (size_t)l * 2 * 768 * 256, bhh + (long)l * 2 * 768, outBuf[l], hfinal);
    inCur = outBuf[l];
    Kin = 512;
  }

  // 4. permute seq-major -> node-major; node_h = node_bidir @ Wmd^T + bmd
  permgather_k<<<T_, 256, 0, stream>>>(inpA, inpB);
  gemm_nt<1, 1, 1, 1><<<dim3(T_ / 64, 4, 1), 256, 0, stream>>>(
      inpB, wWmdH, wWmdL, bmd, node_h, T_, 256, 512, 0L, 0L, 0L, 0L);

  // 5. message passing x3 (3-term split GEMMs: ~fp32 precision)
  for (int it = 0; it < 3; ++it) {
    gemm_nt<0, 1, 1, 0><<<dim3(T_ / 64, 4, 1), 256, 0, stream>>>(
        node_h, wWxH, wWxL, nullptr, Pbuf, T_, 256, 256, 0L, 0L, 0L, 0L);
    aggregate_k<<<T_ / 4, 256, 0, stream>>>(rowptr, eord, srcI, edge_types, Pbuf, pe, agg);
    gemm_nt<0, 1, 1, 1><<<dim3(T_ / 64, 12, 1), 256, 0, stream>>>(
        agg, wCWihH, wCWihL, cbih, gi2, T_, 768, 256, 0L, 0L, 0L, 0L);
    gemm_nt<0, 1, 1, 1><<<dim3(T_ / 64, 12, 1), 256, 0, stream>>>(
        node_h, wCWhhH, wCWhhL, cbhh, gh2, T_, 768, 256, 0L, 0L, 0L, 0L);
    cell_ew_k<<<T_, 256, 0, stream>>>(gi2, gh2, node_h);
  }

  // 6. gated projections (3-term, fp32 out) + per-graph sum + merged
  gemm_nt<0, 1, 1, 0><<<dim3(T_ / 64, 16, 1), 256, 0, stream>>>(
      node_h, wWcatH, wWcatL, nullptr, gatedF, T_, 1024, 256, 0L, 0L, 0L, 0L);
  graph_reduce_k<<<256, 256, 0, stream>>>(gatedF, bgate, bemb, gemb);
  merged_k<<<256, 256, 0, stream>>>(hfinal, gemb, Wglob, bglob, merged);
}

// Round 8
// 1736.656 us; speedup vs baseline: 1.9804x; 1.2622x over previous
//
#include <hip/hip_runtime.h>

typedef __attribute__((ext_vector_type(8))) _Float16 v8h;
typedef __attribute__((ext_vector_type(4))) float v4f;
typedef __attribute__((ext_vector_type(4))) int i4;

#define DEV __device__ __forceinline__

constexpr int S_ = 64;
constexpr int B_ = 256;
constexpr int E_ = 131072;
constexpr int T_ = S_ * B_;   // 16384

DEV float sigm(float x) { return 1.f / (1.f + __expf(-x)); }
DEV float tanh_f(float x) { return 1.f - 2.f / (__expf(2.f * x) + 1.f); }

// MFMA with B operand pinned to AGPRs ("a" constraint) — keeps step-invariant
// weights in the AGPR file without touching the v[0:255] budget.
DEV v4f mfma_ag(v8h a, i4 w, v4f c) {
  asm volatile("v_mfma_f32_16x16x32_f16 %0, %1, %2, %0" : "+v"(c) : "v"(a), "a"(w));
  return c;
}
// Dataflow hazard fence: accumulator threaded THROUGH the nops -> consumers
// ordered after MFMA writes by data dependence (round 6 lesson).
DEV v4f mfma_fence(v4f c) {
  asm volatile("s_nop 7\n\ts_nop 7" : "+v"(c));
  return c;
}
// Async global->LDS copy, 16B per lane (linear LDS dest = base + lane*16).
DEV void async_cp16(const _Float16* g, _Float16* l) {
  __builtin_amdgcn_global_load_lds(
      (const __attribute__((address_space(1))) void*)g,
      (__attribute__((address_space(3))) void*)l, 16, 0, 0);
}
// Raw barrier + counted waits (memory clobber pins loads/stores on their side).
DEV void bar_lgkm() {
  asm volatile("s_waitcnt lgkmcnt(0)" ::: "memory");
  __builtin_amdgcn_s_barrier();
}
DEV void bar_step_end() {
  // 6 prefetch global_load_lds are the OLDEST outstanding vmem ops; up to 16
  // y-stores may remain in flight (nobody reads y this kernel).
  asm volatile("s_waitcnt vmcnt(16) lgkmcnt(0)" ::: "memory");
  __builtin_amdgcn_s_barrier();
}

// ---------------- weight fp32 -> fp16 (hi, optional lo residual) ----------------
struct CJob { const float* s; _Float16* d; _Float16* dlo; int n; int rowLen; int stride; };
struct CJobs { CJob j[9]; };

__global__ __launch_bounds__(256) void convert_k(CJobs jobs) {
  for (int q = 0; q < 9; ++q) {
    CJob jb = jobs.j[q];
    for (int i = blockIdx.x * 256 + threadIdx.x; i < jb.n; i += gridDim.x * 256) {
      int row = i / jb.rowLen;
      int col = i - row * jb.rowLen;
      float f = jb.s[(long)row * jb.stride + col];
      _Float16 hi = (_Float16)f;
      jb.d[i] = hi;
      if (jb.dlo) jb.dlo[i] = (_Float16)(f - (float)hi);
    }
  }
}

// ---------------- node embedding gather (fp32 table -> fp16) ----------------
__global__ __launch_bounds__(256) void embed_k(const int* __restrict__ nt,
                                               const float* __restrict__ tab,
                                               _Float16* __restrict__ x0) {
  int t = blockIdx.x, j = threadIdx.x;
  x0[(long)t * 256 + j] = (_Float16)tab[nt[t] * 256 + j];
}

// ---------------- per-edge-type bias: pe[16][256] = edge_table @ W_e^T + bmsg (fp32 exact) ----------------
__global__ __launch_bounds__(256) void pe_k(const float* __restrict__ etab,
                                            const float* __restrict__ Wmsg,
                                            const float* __restrict__ bmsg,
                                            float* __restrict__ pe) {
  int j = threadIdx.x;
  const float* w = Wmsg + (long)j * 512 + 256;  // W_e = Wmsg[:, 256:512]
  for (int r = 0; r < 16; ++r) {
    float acc = bmsg[j];
    const float* e = etab + r * 256;
    for (int k = 0; k < 256; ++k) acc += e[k] * w[k];
    pe[r * 256 + j] = acc;
  }
}

// ---------------- CSR build (by dst) ----------------
__global__ __launch_bounds__(256) void count_k(const int* __restrict__ dst, int* __restrict__ cnt) {
  int e = blockIdx.x * 256 + threadIdx.x;
  if (e < E_) atomicAdd(&cnt[dst[e]], 1);
}

__global__ __launch_bounds__(256) void csr_scan_k(const int* __restrict__ cnt,
                                                  int* __restrict__ rowptr,
                                                  int* __restrict__ cur) {
  __shared__ int ps[256];
  int tid = threadIdx.x;
  int base = tid * 64;
  int s = 0;
  for (int i = 0; i < 64; ++i) s += cnt[base + i];
  ps[tid] = s;
  __syncthreads();
  for (int d = 1; d < 256; d <<= 1) {
    int v = (tid >= d) ? ps[tid - d] : 0;
    __syncthreads();
    ps[tid] += v;
    __syncthreads();
  }
  int run = (tid == 0) ? 0 : ps[tid - 1];
  for (int i = 0; i < 64; ++i) {
    rowptr[base + i] = run;
    cur[base + i] = run;
    run += cnt[base + i];
  }
  if (tid == 255) rowptr[T_] = run;
}

__global__ __launch_bounds__(256) void fill_k(const int* __restrict__ dst,
                                              int* __restrict__ cur,
                                              int* __restrict__ eord) {
  int e = blockIdx.x * 256 + threadIdx.x;
  if (e < E_) {
    int p = atomicAdd(&cur[dst[e]], 1);
    eord[p] = e;
  }
}

// ---------------- MFMA GEMM: C[M,N] = A[M,K] @ W[N,K]^T (+bias) ----------------
// AH=1: A is fp16 (plain). AH=0: A is fp32, split on the fly into fp16 hi+lo.
// WLO=1: W has a lo residual (adds a_hi*w_lo term).
template <int AH, int WLO, int C32, int BIAS>
__global__ __launch_bounds__(256) void gemm_nt(const void* __restrict__ Ap,
                                               const _Float16* __restrict__ Wp,
                                               const _Float16* __restrict__ Wlp,
                                               const float* __restrict__ bias,
                                               void* __restrict__ Cp,
                                               int M, int N, int K,
                                               long sA, long sW, long sB, long sC) {
  __shared__ _Float16 As[64][40];
  __shared__ _Float16 Al[64][40];
  __shared__ _Float16 Bs[64][40];
  __shared__ _Float16 Bl[64][40];
  const int bz = blockIdx.z;
  const int m0 = blockIdx.x * 64, n0 = blockIdx.y * 64;
  const int tid = threadIdx.x, lane = tid & 63, wv = tid >> 6;
  const int wy = wv >> 1, wx = wv & 1;
  const int sr = tid >> 2, skc = tid & 3;
  const _Float16* W = Wp + bz * sW;
  v4f z4 = {0.f, 0.f, 0.f, 0.f};
  v4f acc[2][2];
  acc[0][0] = z4; acc[0][1] = z4; acc[1][0] = z4; acc[1][1] = z4;

  for (int k0 = 0; k0 < K; k0 += 32) {
    if constexpr (AH) {
      const _Float16* A = (const _Float16*)Ap + bz * sA;
      *(v8h*)&As[sr][skc * 8] = *(const v8h*)(A + (long)(m0 + sr) * K + k0 + skc * 8);
    } else {
      const float* A = (const float*)Ap + bz * sA;
      const float* p = A + (long)(m0 + sr) * K + k0 + skc * 8;
      v4f f0 = *(const v4f*)p;
      v4f f1 = *(const v4f*)(p + 4);
      v8h hv, lv;
#pragma unroll
      for (int j = 0; j < 4; ++j) {
        hv[j] = (_Float16)f0[j]; lv[j] = (_Float16)(f0[j] - (float)hv[j]);
        hv[4 + j] = (_Float16)f1[j]; lv[4 + j] = (_Float16)(f1[j] - (float)hv[4 + j]);
      }
      *(v8h*)&As[sr][skc * 8] = hv;
      *(v8h*)&Al[sr][skc * 8] = lv;
    }
    *(v8h*)&Bs[sr][skc * 8] = *(const v8h*)(W + (long)(n0 + sr) * K + k0 + skc * 8);
    if constexpr (WLO)
      *(v8h*)&Bl[sr][skc * 8] = *(const v8h*)(Wlp + bz * sW + (long)(n0 + sr) * K + k0 + skc * 8);
    __syncthreads();
    const int fr = lane & 15, fk = (lane >> 4) * 8;
    v8h ah[2], alr[2], bh[2], blr[2];
    ah[0] = *(v8h*)&As[wy * 32 + fr][fk];
    ah[1] = *(v8h*)&As[wy * 32 + 16 + fr][fk];
    bh[0] = *(v8h*)&Bs[wx * 32 + fr][fk];
    bh[1] = *(v8h*)&Bs[wx * 32 + 16 + fr][fk];
    if constexpr (!AH) {
      alr[0] = *(v8h*)&Al[wy * 32 + fr][fk];
      alr[1] = *(v8h*)&Al[wy * 32 + 16 + fr][fk];
    }
    if constexpr (WLO) {
      blr[0] = *(v8h*)&Bl[wx * 32 + fr][fk];
      blr[1] = *(v8h*)&Bl[wx * 32 + 16 + fr][fk];
    }
#pragma unroll
    for (int mi = 0; mi < 2; ++mi)
#pragma unroll
      for (int ni = 0; ni < 2; ++ni) {
        acc[mi][ni] = __builtin_amdgcn_mfma_f32_16x16x32_f16(ah[mi], bh[ni], acc[mi][ni], 0, 0, 0);
        if constexpr (!AH)
          acc[mi][ni] = __builtin_amdgcn_mfma_f32_16x16x32_f16(alr[mi], bh[ni], acc[mi][ni], 0, 0, 0);
        if constexpr (WLO)
          acc[mi][ni] = __builtin_amdgcn_mfma_f32_16x16x32_f16(ah[mi], blr[ni], acc[mi][ni], 0, 0, 0);
      }
    __syncthreads();
  }
  const int fr = lane & 15, fq = lane >> 4;
#pragma unroll
  for (int mi = 0; mi < 2; ++mi)
#pragma unroll
    for (int ni = 0; ni < 2; ++ni)
#pragma unroll
      for (int j = 0; j < 4; ++j) {
        int row = m0 + wy * 32 + mi * 16 + fq * 4 + j;
        int col = n0 + wx * 32 + ni * 16 + fr;
        float v = acc[mi][ni][j];
        if (BIAS) v += bias[bz * sB + col];
        if (C32)
          ((float*)Cp)[bz * sC + (long)row * N + col] = v;
        else
          ((_Float16*)Cp)[bz * sC + (long)row * N + col] = (_Float16)v;
      }
}

// ---------------- recurrent GRU layer: AGPR-weight-resident + gi LDS prefetch ----------------
// Block = 16 batch rows x 1 dir, 4 waves. Wave w owns cols [w*64, w*64+64).
// r,z weights -> AGPRs (asm MFMA "a" operands); n-gate ht0..2 -> LDS 96KB; ht3 -> VGPR.
// gi tile (24KB/step, contiguous) double-buffered in LDS via global_load_lds,
// prefetched one step ahead; raw s_barrier + counted waitcnt keeps it in flight.
__global__ __launch_bounds__(256, 1) void gru_layer_k(const _Float16* __restrict__ gi,   // (2,T,768) fp16, bih included
                                                      const _Float16* __restrict__ Whh,  // (2,768,256) fp16
                                                      const float* __restrict__ bhh,     // (2,768)
                                                      _Float16* __restrict__ y,          // (T,512) fp16
                                                      float* __restrict__ hfinal) {      // (2,256,256) fp32
  __shared__ _Float16 wlds[49152];     // 96KB: n-gate ht<3, [kch][w][ht][col16][8]
  __shared__ _Float16 hb[4096];        // 8KB: h fp16, [kc][fq][row][8]
  __shared__ _Float16 gib[2][12288];   // 48KB: gi tile double buffer (16 rows x 768)
  const int dir = blockIdx.y;
  const int r0 = blockIdx.x * 16;
  const int tid = threadIdx.x, lane = tid & 63, w = tid >> 6;
  const int fr = lane & 15, fq = lane >> 4;
  const _Float16* Wd = Whh + (long)dir * 768 * 256;
  const _Float16* gid = gi + (long)dir * T_ * 768;

  // stage n-gate ht-tiles 0..2 into LDS: i = ((kch*4 + w)*3 + ht)*16 + c16
  for (int i = tid; i < 6144; i += 256) {
    int c16 = i & 15;
    int r = i >> 4;
    int ht = r % 3; r /= 3;
    int wq = r & 3;
    int kch = r >> 2;
    int col = wq * 64 + ht * 16 + c16;
    *(v8h*)&wlds[(size_t)i * 8] = *(const v8h*)(Wd + (long)(512 + col) * 256 + kch * 8);
  }
  for (int i = tid; i < 2048; i += 256) ((int*)hb)[i] = 0;

  // r,z weights -> AGPR-destined arrays; n ht=3 tile -> VGPR
  i4 wr[4][8], wz[4][8];
  v8h wn3[8];
#pragma unroll
  for (int ht = 0; ht < 4; ++ht)
#pragma unroll
    for (int kc = 0; kc < 8; ++kc) {
      wr[ht][kc] = *(const i4*)(Wd + (long)(w * 64 + ht * 16 + fr) * 256 + kc * 32 + fq * 8);
      wz[ht][kc] = *(const i4*)(Wd + (long)(256 + w * 64 + ht * 16 + fr) * 256 + kc * 32 + fq * 8);
    }
#pragma unroll
  for (int kc = 0; kc < 8; ++kc)
    wn3[kc] = *(const v8h*)(Wd + (long)(512 + w * 64 + 48 + fr) * 256 + kc * 32 + fq * 8);

  float bhv[3][4];
#pragma unroll
  for (int g = 0; g < 3; ++g)
#pragma unroll
    for (int ht = 0; ht < 4; ++ht)
      bhv[g][ht] = bhh[(long)dir * 768 + g * 256 + w * 64 + ht * 16 + fr];

  float hreg[4][4];
#pragma unroll
  for (int a0 = 0; a0 < 4; ++a0)
#pragma unroll
    for (int b0 = 0; b0 < 4; ++b0) hreg[a0][b0] = 0.f;

  // prefetch gi tile for the first step
  {
    const _Float16* gb = gid + ((long)(dir ? 63 : 0) * 256 + r0) * 768;
#pragma unroll
    for (int c = 0; c < 6; ++c)
      async_cp16(gb + c * 2048 + tid * 8, &gib[0][c * 2048 + tid * 8]);
  }
  __syncthreads();  // full drain: weights + hb staged, first tile landed

  const v4f z4 = {0.f, 0.f, 0.f, 0.f};
  int cur = 0;
  for (int step = 0; step < 64; ++step) {
    const int t = dir ? 63 - step : step;
    // read h fragments (prev step): a[kc] = h[row=fr][k=kc*32+fq*8+0..7]
    v8h a[8];
#pragma unroll
    for (int kc = 0; kc < 8; ++kc)
      a[kc] = *(const v8h*)&hb[((kc * 4 + fq) * 16 + fr) * 8];
    // prefetch next step's gi tile into the other buffer (stays in flight
    // across the raw barrier below — no vmcnt drain here)
    if (step < 63) {
      const _Float16* gb = gid + ((long)(dir ? 62 - step : step + 1) * 256 + r0) * 768;
#pragma unroll
      for (int c = 0; c < 6; ++c)
        async_cp16(gb + c * 2048 + tid * 8, &gib[cur ^ 1][c * 2048 + tid * 8]);
    }
    bar_lgkm();  // h reads retired; waves synced; prefetch still outstanding

    const _Float16* gl = &gib[cur][(fq * 4) * 768 + w * 64 + fr];
#pragma unroll
    for (int ht = 0; ht < 4; ++ht) {
      v4f cr = z4, cz = z4, cn = z4;
#pragma unroll
      for (int kc = 0; kc < 8; ++kc) {
        cr = mfma_ag(a[kc], wr[ht][kc], cr);
        cz = mfma_ag(a[kc], wz[ht][kc], cz);
        v8h w2 = (ht < 3) ? *(const v8h*)&wlds[((((kc * 4 + fq) * 4 + w) * 3 + ht) * 16 + fr) * 8]
                          : wn3[kc];
        cn = __builtin_amdgcn_mfma_f32_16x16x32_f16(a[kc], w2, cn, 0, 0, 0);
      }
      cr = mfma_fence(cr);
      cz = mfma_fence(cz);
#pragma unroll
      for (int j = 0; j < 4; ++j) {
        float gr = (float)gl[j * 768 + ht * 16];
        float gz = (float)gl[j * 768 + 256 + ht * 16];
        float gn = (float)gl[j * 768 + 512 + ht * 16];
        float rr = sigm(gr + cr[j] + bhv[0][ht]);
        float zz = sigm(gz + cz[j] + bhv[1][ht]);
        float nn = tanh_f(gn + rr * (cn[j] + bhv[2][ht]));
        float hnew = (1.f - zz) * nn + zz * hreg[ht][j];
        hreg[ht][j] = hnew;
        y[((long)t * 256 + r0 + fq * 4 + j) * 512 + (long)dir * 256 + w * 64 + ht * 16 + fr] = (_Float16)hnew;
        int col = w * 64 + ht * 16 + fr;
        hb[(((col >> 5) * 4 + ((col >> 3) & 3)) * 16 + (fq * 4 + j)) * 8 + (col & 7)] = (_Float16)hnew;
      }
    }
    bar_step_end();  // hb writes visible; prefetch (oldest 6 vmem) completed
    cur ^= 1;
  }
#pragma unroll
  for (int ht = 0; ht < 4; ++ht)
#pragma unroll
    for (int j = 0; j < 4; ++j)
      hfinal[((long)dir * 256 + r0 + fq * 4 + j) * 256 + w * 64 + ht * 16 + fr] = hreg[ht][j];
}

// ---------------- seq-major -> node-major permutation (fp16 rows of 512) ----------------
__global__ __launch_bounds__(256) void permgather_k(const _Float16* __restrict__ inp, _Float16* __restrict__ nb) {
  int t = blockIdx.x, tid = threadIdx.x;
  const unsigned* s = (const unsigned*)(inp + ((long)(t & 63) * 256 + (t >> 6)) * 512);
  unsigned* d = (unsigned*)(nb + (long)t * 512);
  d[tid] = s[tid];
}

// ---------------- CSR aggregation: agg[v] = sum_{e: dst=v} P[src[e]] + pe[et[e]] ----------------
__global__ __launch_bounds__(256) void aggregate_k(const int* __restrict__ rowptr,
                                                   const int* __restrict__ eord,
                                                   const int* __restrict__ src,
                                                   const int* __restrict__ et,
                                                   const float* __restrict__ P,
                                                   const float* __restrict__ pe,
                                                   float* __restrict__ agg) {
  int v = blockIdx.x * 4 + (threadIdx.x >> 6);
  int lane = threadIdx.x & 63;
  int b0 = rowptr[v], b1 = rowptr[v + 1];
  v4f acc = {0.f, 0.f, 0.f, 0.f};
  for (int i = b0; i < b1; ++i) {
    int e = eord[i];
    int s = src[e], ty = et[e];
    v4f pv = *(const v4f*)(P + (long)s * 256 + lane * 4);
    v4f ev = *(const v4f*)(pe + ty * 256 + lane * 4);
    acc += pv + ev;
  }
  *(v4f*)(agg + (long)v * 256 + lane * 4) = acc;
}

// ---------------- GRU cell elementwise (biases already in gi2/gh2) ----------------
__global__ __launch_bounds__(256) void cell_ew_k(const float* __restrict__ gi2,
                                                 const float* __restrict__ gh2,
                                                 float* __restrict__ nodeh) {
  int node = blockIdx.x, j = threadIdx.x;
  const float* a = gi2 + (long)node * 768;
  const float* b = gh2 + (long)node * 768;
  float rr = sigm(a[j] + b[j]);
  float zz = sigm(a[j + 256] + b[j + 256]);
  float nn = tanh_f(a[j + 512] + rr * b[j + 512]);
  float h = nodeh[(long)node * 256 + j];
  nodeh[(long)node * 256 + j] = (1.f - zz) * nn + zz * h;
}

// ---------------- gated sum per graph (fp32 pre-activations) ----------------
__global__ __launch_bounds__(256) void graph_reduce_k(const float* __restrict__ gt,
                                                      const float* __restrict__ bgate,
                                                      const float* __restrict__ bemb,
                                                      float* __restrict__ ge) {
  int g = blockIdx.x, tid = threadIdx.x;
  for (int col = tid; col < 512; col += 256) {
    float bg = bgate[col], be = bemb[col];
    float acc = 0.f;
    for (int p = 0; p < 64; ++p) {
      const float* row = gt + ((long)g * 64 + p) * 1024;
      acc += sigm(row[col] + bg) * (row[512 + col] + be);
    }
    ge[(long)g * 512 + col] = acc;
  }
}

// ---------------- merged = [hf|hb|graph_emb] @ Wglob^T + bglob (fp32) ----------------
__global__ __launch_bounds__(256) void merged_k(const float* __restrict__ hfinal,
                                                const float* __restrict__ ge,
                                                const float* __restrict__ Wglob,
                                                const float* __restrict__ bglob,
                                                float* __restrict__ out) {
  __shared__ float vec[1024];
  int g = blockIdx.x, tid = threadIdx.x;
  vec[tid] = hfinal[(long)g * 256 + tid];
  vec[256 + tid] = hfinal[(long)65536 + g * 256 + tid];
  vec[512 + tid] = ge[(long)g * 512 + tid];
  vec[768 + tid] = ge[(long)g * 512 + 256 + tid];
  __syncthreads();
  const float* wr = Wglob + (long)tid * 1024;
  float acc = bglob[tid];
  for (int k = 0; k < 1024; ++k) acc += vec[k] * wr[k];
  out[(long)g * 256 + tid] = acc;
}

// =========================== host ===========================
extern "C" void kernel_launch(void* const* d_in, const int* in_sizes, int n_in,
                              void* d_out, int out_size, void* d_ws, size_t ws_size,
                              hipStream_t stream) {
  (void)in_sizes; (void)n_in; (void)out_size; (void)ws_size;
  const float* node_table = (const float*)d_in[0];
  const float* Wih_l0 = (const float*)d_in[1];
  const float* Wih_l12 = (const float*)d_in[2];
  const float* WhhF = (const float*)d_in[3];
  const float* bih = (const float*)d_in[4];
  const float* bhh = (const float*)d_in[5];
  const float* WmdF = (const float*)d_in[6];
  const float* bmd = (const float*)d_in[7];
  const float* edge_table = (const float*)d_in[8];
  const float* Wmsg = (const float*)d_in[9];
  const float* bmsg = (const float*)d_in[10];
  const float* cWih = (const float*)d_in[11];
  const float* cWhh = (const float*)d_in[12];
  const float* cbih = (const float*)d_in[13];
  const float* cbhh = (const float*)d_in[14];
  const float* Wgate = (const float*)d_in[15];
  const float* bgate = (const float*)d_in[16];
  const float* Wemb = (const float*)d_in[17];
  const float* bemb = (const float*)d_in[18];
  const float* Wglob = (const float*)d_in[19];
  const float* bglob = (const float*)d_in[20];
  const int* node_types = (const int*)d_in[21];
  const int* edge_types = (const int*)d_in[22];
  const int* srcI = (const int*)d_in[23];
  const int* dstI = (const int*)d_in[24];

  float* node_h = (float*)d_out;                  // (T,256) = output 0, used as working buffer
  float* merged = (float*)d_out + (long)T_ * 256; // (256,256) = output 1

  char* w = (char*)d_ws;
  size_t off = 0;
  auto alloc = [&](size_t bytes) -> char* {
    char* ptr = w + off;
    off = (off + bytes + 255) & ~(size_t)255;
    return ptr;
  };
  _Float16* wWih0H = (_Float16*)alloc((size_t)2 * 768 * 256 * 2);
  _Float16* wWih0L = (_Float16*)alloc((size_t)2 * 768 * 256 * 2);
  _Float16* wWih12H = (_Float16*)alloc((size_t)2 * 2 * 768 * 512 * 2);
  _Float16* wWih12L = (_Float16*)alloc((size_t)2 * 2 * 768 * 512 * 2);
  _Float16* wWhh = (_Float16*)alloc((size_t)3 * 2 * 768 * 256 * 2);
  _Float16* wWmdH = (_Float16*)alloc((size_t)256 * 512 * 2);
  _Float16* wWmdL = (_Float16*)alloc((size_t)256 * 512 * 2);
  _Float16* wWxH = (_Float16*)alloc((size_t)256 * 256 * 2);
  _Float16* wWxL = (_Float16*)alloc((size_t)256 * 256 * 2);
  _Float16* wCWihH = (_Float16*)alloc((size_t)768 * 256 * 2);
  _Float16* wCWihL = (_Float16*)alloc((size_t)768 * 256 * 2);
  _Float16* wCWhhH = (_Float16*)alloc((size_t)768 * 256 * 2);
  _Float16* wCWhhL = (_Float16*)alloc((size_t)768 * 256 * 2);
  _Float16* wWcatH = (_Float16*)alloc((size_t)1024 * 256 * 2);
  _Float16* wWcatL = (_Float16*)alloc((size_t)1024 * 256 * 2);
  _Float16* inpA = (_Float16*)alloc((size_t)T_ * 512 * 2);
  _Float16* inpB = (_Float16*)alloc((size_t)T_ * 512 * 2);
  float* agg = (float*)alloc((size_t)T_ * 256 * 4);
  float* hfinal = (float*)alloc((size_t)2 * 256 * 256 * 4);
  float* pe = (float*)alloc((size_t)16 * 256 * 4);
  int* cnt = (int*)alloc((size_t)T_ * 4);
  int* rowptr = (int*)alloc((size_t)(T_ + 1) * 4);
  int* cur = (int*)alloc((size_t)T_ * 4);
  int* eord = (int*)alloc((size_t)E_ * 4);
  float* gemb = (float*)alloc((size_t)256 * 512 * 4);
  // Union region, 112 MB: phases do not overlap in time.
  //   GRU phase:  gi (2,T,768) fp16 = 48 MB @ +0 ; x0 (T,256) fp16 = 8 MB @ +96M
  //   MP phase:   Pbuf (T,256) = 16 MB @ +0 ; gi2 (T,768) = 48 MB @ +16M ; gh2 @ +64M
  //   epilogue:   gated (T,1024) fp32 = 64 MB @ +0
  char* R = alloc((size_t)112 * 1024 * 1024);
  _Float16* gi = (_Float16*)R;
  _Float16* x0 = (_Float16*)(R + (size_t)96 * 1024 * 1024);
  float* Pbuf = (float*)R;
  float* gi2 = (float*)(R + (size_t)16 * 1024 * 1024);
  float* gh2 = (float*)(R + (size_t)64 * 1024 * 1024);
  float* gatedF = (float*)R;

  // 1. weights -> fp16 hi (+ lo residual where W-systematic error matters downstream)
  CJobs jobs;
  jobs.j[0] = {Wih_l0, wWih0H, wWih0L, 2 * 768 * 256, 2 * 768 * 256, 2 * 768 * 256};
  jobs.j[1] = {Wih_l12, wWih12H, wWih12L, 2 * 2 * 768 * 512, 2 * 2 * 768 * 512, 2 * 2 * 768 * 512};
  jobs.j[2] = {WhhF, wWhh, nullptr, 3 * 2 * 768 * 256, 3 * 2 * 768 * 256, 3 * 2 * 768 * 256};
  jobs.j[3] = {WmdF, wWmdH, wWmdL, 256 * 512, 256 * 512, 256 * 512};
  jobs.j[4] = {Wmsg, wWxH, wWxL, 256 * 256, 256, 512};  // W_x = Wmsg[:, :256]
  jobs.j[5] = {cWih, wCWihH, wCWihL, 768 * 256, 768 * 256, 768 * 256};
  jobs.j[6] = {cWhh, wCWhhH, wCWhhL, 768 * 256, 768 * 256, 768 * 256};
  jobs.j[7] = {Wgate, wWcatH, wWcatL, 512 * 256, 512 * 256, 512 * 256};
  jobs.j[8] = {Wemb, wWcatH + 512 * 256, wWcatL + 512 * 256, 512 * 256, 512 * 256, 512 * 256};
  convert_k<<<1024, 256, 0, stream>>>(jobs);

  // 2. embeddings, edge-type bias, CSR
  embed_k<<<T_, 256, 0, stream>>>(node_types, node_table, x0);
  pe_k<<<1, 256, 0, stream>>>(edge_table, Wmsg, bmsg, pe);
  hipMemsetAsync(cnt, 0, (size_t)T_ * 4, stream);
  count_k<<<E_ / 256, 256, 0, stream>>>(dstI, cnt);
  csr_scan_k<<<1, 256, 0, stream>>>(cnt, rowptr, cur);
  fill_k<<<E_ / 256, 256, 0, stream>>>(dstI, cur, eord);

  // 3. three bidirectional GRU layers (gi fp16 2-term GEMM; AGPR-resident recurrence)
  const _Float16* inCur = x0;
  _Float16* outBuf[3] = {inpA, inpB, inpA};
  int Kin = 256;
  for (int l = 0; l < 3; ++l) {
    const _Float16 *WlH, *WlL;
    long sW;
    if (l == 0) { WlH = wWih0H; WlL = wWih0L; sW = (long)768 * 256; }
    else {
      WlH = wWih12H + (size_t)(l - 1) * 2 * 768 * 512;
      WlL = wWih12L + (size_t)(l - 1) * 2 * 768 * 512;
      sW = (long)768 * 512;
    }
    gemm_nt<1, 1, 0, 1><<<dim3(T_ / 64, 12, 2), 256, 0, stream>>>(
        inCur, WlH, WlL, bih + (long)l * 2 * 768, gi, T_, 768, Kin, 0L, sW, 768L, (long)T_ * 768);
    gru_layer_k<<<dim3(16, 2), 256, 0, stream>>>(
        gi, wWhh + (size_t)l * 2 * 768 * 256, bhh + (long)l * 2 * 768, outBuf[l], hfinal);
    inCur = outBuf[l];
    Kin = 512;
  }

  // 4. permute seq-major -> node-major; node_h = node_bidir @ Wmd^T + bmd
  permgather_k<<<T_, 256, 0, stream>>>(inpA, inpB);
  gemm_nt<1, 1, 1, 1><<<dim3(T_ / 64, 4, 1), 256, 0, stream>>>(
      inpB, wWmdH, wWmdL, bmd, node_h, T_, 256, 512, 0L, 0L, 0L, 0L);

  // 5. message passing x3 (3-term split GEMMs: ~fp32 precision)
  for (int it = 0; it < 3; ++it) {
    gemm_nt<0, 1, 1, 0><<<dim3(T_ / 64, 4, 1), 256, 0, stream>>>(
        node_h, wWxH, wWxL, nullptr, Pbuf, T_, 256, 256, 0L, 0L, 0L, 0L);
    aggregate_k<<<T_ / 4, 256, 0, stream>>>(rowptr, eord, srcI, edge_types, Pbuf, pe, agg);
    gemm_nt<0, 1, 1, 1><<<dim3(T_ / 64, 12, 1), 256, 0, stream>>>(
        agg, wCWihH, wCWihL, cbih, gi2, T_, 768, 256, 0L, 0L, 0L, 0L);
    gemm_nt<0, 1, 1, 1><<<dim3(T_ / 64, 12, 1), 256, 0, stream>>>(
        node_h, wCWhhH, wCWhhL, cbhh, gh2, T_, 768, 256, 0L, 0L, 0L, 0L);
    cell_ew_k<<<T_, 256, 0, stream>>>(gi2, gh2, node_h);
  }

  // 6. gated projections (3-term, fp32 out) + per-graph sum + merged
  gemm_nt<0, 1, 1, 0><<<dim3(T_ / 64, 16, 1), 256, 0, stream>>>(
      node_h, wWcatH, wWcatL, nullptr, gatedF, T_, 1024, 256, 0L, 0L, 0L, 0L);
  graph_reduce_k<<<256, 256, 0, stream>>>(gatedF, bgate, bemb, gemb);
  merged_k<<<256, 256, 0, stream>>>(hfinal, gemb, Wglob, bglob, merged);
}

// Round 12
// 1480.241 us; speedup vs baseline: 2.3234x; 1.1732x over previous
//
#include <hip/hip_runtime.h>

typedef __attribute__((ext_vector_type(8))) _Float16 v8h;
typedef __attribute__((ext_vector_type(4))) float v4f;
typedef __attribute__((ext_vector_type(4))) int i4;

#define DEV __device__ __forceinline__

constexpr int S_ = 64;
constexpr int B_ = 256;
constexpr int E_ = 131072;
constexpr int T_ = S_ * B_;   // 16384

DEV float sigm(float x) { return 1.f / (1.f + __expf(-x)); }
DEV float tanh_f(float x) { return 1.f - 2.f / (__expf(2.f * x) + 1.f); }

// MFMA with B operand pinned to AGPRs ("a" constraint) — keeps step-invariant
// weights in the AGPR file without touching the VGPR budget.
DEV v4f mfma_ag(v8h a, i4 w, v4f c) {
  asm volatile("v_mfma_f32_16x16x32_f16 %0, %1, %2, %0" : "+v"(c) : "v"(a), "a"(w));
  return c;
}
// Dataflow hazard fence: accumulator threaded THROUGH the nops -> consumers
// ordered after MFMA writes by data dependence (round 6 lesson).
DEV v4f mfma_fence(v4f c) {
  asm volatile("s_nop 7\n\ts_nop 7" : "+v"(c));
  return c;
}
// Async global->LDS copy, 16B per lane (linear LDS dest = base + lane*16).
DEV void async_cp16(const _Float16* g, _Float16* l) {
  __builtin_amdgcn_global_load_lds(
      (const __attribute__((address_space(1))) void*)g,
      (__attribute__((address_space(3))) void*)l, 16, 0, 0);
}
// Raw barrier + counted waits (memory clobber pins loads/stores on their side).
DEV void bar_lgkm() {
  asm volatile("s_waitcnt lgkmcnt(0)" ::: "memory");
  __builtin_amdgcn_s_barrier();
}
DEV void bar_step_end() {
  // per wave/step: the 3 prefetch global_load_lds are issued BEFORE the 8
  // y-stores, so waiting to <=8 outstanding retires all prefetches (and any
  // older stores). y-stores may stay in flight (nobody reads y here).
  asm volatile("s_waitcnt vmcnt(8) lgkmcnt(0)" ::: "memory");
  __builtin_amdgcn_s_barrier();
}

// ---------------- weight fp32 -> fp16 (hi, optional lo residual) ----------------
struct CJob { const float* s; _Float16* d; _Float16* dlo; int n; int rowLen; int stride; };
struct CJobs { CJob j[9]; };

__global__ __launch_bounds__(256) void convert_k(CJobs jobs) {
  for (int q = 0; q < 9; ++q) {
    CJob jb = jobs.j[q];
    for (int i = blockIdx.x * 256 + threadIdx.x; i < jb.n; i += gridDim.x * 256) {
      int row = i / jb.rowLen;
      int col = i - row * jb.rowLen;
      float f = jb.s[(long)row * jb.stride + col];
      _Float16 hi = (_Float16)f;
      jb.d[i] = hi;
      if (jb.dlo) jb.dlo[i] = (_Float16)(f - (float)hi);
    }
  }
}

// ---------------- node embedding gather (fp32 table -> fp16) ----------------
__global__ __launch_bounds__(256) void embed_k(const int* __restrict__ nt,
                                               const float* __restrict__ tab,
                                               _Float16* __restrict__ x0) {
  int t = blockIdx.x, j = threadIdx.x;
  x0[(long)t * 256 + j] = (_Float16)tab[nt[t] * 256 + j];
}

// ---------------- per-edge-type bias: pe[16][256] = edge_table @ W_e^T + bmsg (fp32 exact) ----------------
__global__ __launch_bounds__(256) void pe_k(const float* __restrict__ etab,
                                            const float* __restrict__ Wmsg,
                                            const float* __restrict__ bmsg,
                                            float* __restrict__ pe) {
  int j = threadIdx.x;
  const float* w = Wmsg + (long)j * 512 + 256;  // W_e = Wmsg[:, 256:512]
  for (int r = 0; r < 16; ++r) {
    float acc = bmsg[j];
    const float* e = etab + r * 256;
    for (int k = 0; k < 256; ++k) acc += e[k] * w[k];
    pe[r * 256 + j] = acc;
  }
}

// ---------------- CSR build (by dst) ----------------
__global__ __launch_bounds__(256) void count_k(const int* __restrict__ dst, int* __restrict__ cnt) {
  int e = blockIdx.x * 256 + threadIdx.x;
  if (e < E_) atomicAdd(&cnt[dst[e]], 1);
}

__global__ __launch_bounds__(256) void csr_scan_k(const int* __restrict__ cnt,
                                                  int* __restrict__ rowptr,
                                                  int* __restrict__ cur) {
  __shared__ int ps[256];
  int tid = threadIdx.x;
  int base = tid * 64;
  int s = 0;
  for (int i = 0; i < 64; ++i) s += cnt[base + i];
  ps[tid] = s;
  __syncthreads();
  for (int d = 1; d < 256; d <<= 1) {
    int v = (tid >= d) ? ps[tid - d] : 0;
    __syncthreads();
    ps[tid] += v;
    __syncthreads();
  }
  int run = (tid == 0) ? 0 : ps[tid - 1];
  for (int i = 0; i < 64; ++i) {
    rowptr[base + i] = run;
    cur[base + i] = run;
    run += cnt[base + i];
  }
  if (tid == 255) rowptr[T_] = run;
}

__global__ __launch_bounds__(256) void fill_k(const int* __restrict__ dst,
                                              int* __restrict__ cur,
                                              int* __restrict__ eord) {
  int e = blockIdx.x * 256 + threadIdx.x;
  if (e < E_) {
    int p = atomicAdd(&cur[dst[e]], 1);
    eord[p] = e;
  }
}

// ---------------- MFMA GEMM: C[M,N] = A[M,K] @ W[N,K]^T (+bias) ----------------
// AH=1: A fp16 plain. AH=0: A fp32, converted to fp16 hi (+lo term if ALO).
// WLO=1: W has a lo residual (adds a_hi*w_lo term).
template <int AH, int ALO, int WLO, int C32, int BIAS>
__global__ __launch_bounds__(256) void gemm_nt(const void* __restrict__ Ap,
                                               const _Float16* __restrict__ Wp,
                                               const _Float16* __restrict__ Wlp,
                                               const float* __restrict__ bias,
                                               void* __restrict__ Cp,
                                               int M, int N, int K,
                                               long sA, long sW, long sB, long sC) {
  __shared__ _Float16 As[64][40];
  __shared__ _Float16 Al[64][40];
  __shared__ _Float16 Bs[64][40];
  __shared__ _Float16 Bl[64][40];
  const int bz = blockIdx.z;
  const int m0 = blockIdx.x * 64, n0 = blockIdx.y * 64;
  const int tid = threadIdx.x, lane = tid & 63, wv = tid >> 6;
  const int wy = wv >> 1, wx = wv & 1;
  const int sr = tid >> 2, skc = tid & 3;
  const _Float16* W = Wp + bz * sW;
  v4f z4 = {0.f, 0.f, 0.f, 0.f};
  v4f acc[2][2];
  acc[0][0] = z4; acc[0][1] = z4; acc[1][0] = z4; acc[1][1] = z4;

  for (int k0 = 0; k0 < K; k0 += 32) {
    if constexpr (AH) {
      const _Float16* A = (const _Float16*)Ap + bz * sA;
      *(v8h*)&As[sr][skc * 8] = *(const v8h*)(A + (long)(m0 + sr) * K + k0 + skc * 8);
    } else {
      const float* A = (const float*)Ap + bz * sA;
      const float* p = A + (long)(m0 + sr) * K + k0 + skc * 8;
      v4f f0 = *(const v4f*)p;
      v4f f1 = *(const v4f*)(p + 4);
      v8h hv, lv;
#pragma unroll
      for (int j = 0; j < 4; ++j) {
        hv[j] = (_Float16)f0[j];
        hv[4 + j] = (_Float16)f1[j];
        if constexpr (ALO) {
          lv[j] = (_Float16)(f0[j] - (float)hv[j]);
          lv[4 + j] = (_Float16)(f1[j] - (float)hv[4 + j]);
        }
      }
      *(v8h*)&As[sr][skc * 8] = hv;
      if constexpr (ALO) *(v8h*)&Al[sr][skc * 8] = lv;
    }
    *(v8h*)&Bs[sr][skc * 8] = *(const v8h*)(W + (long)(n0 + sr) * K + k0 + skc * 8);
    if constexpr (WLO)
      *(v8h*)&Bl[sr][skc * 8] = *(const v8h*)(Wlp + bz * sW + (long)(n0 + sr) * K + k0 + skc * 8);
    __syncthreads();
    const int fr = lane & 15, fk = (lane >> 4) * 8;
    v8h ah[2], alr[2], bh[2], blr[2];
    ah[0] = *(v8h*)&As[wy * 32 + fr][fk];
    ah[1] = *(v8h*)&As[wy * 32 + 16 + fr][fk];
    bh[0] = *(v8h*)&Bs[wx * 32 + fr][fk];
    bh[1] = *(v8h*)&Bs[wx * 32 + 16 + fr][fk];
    if constexpr (ALO) {
      alr[0] = *(v8h*)&Al[wy * 32 + fr][fk];
      alr[1] = *(v8h*)&Al[wy * 32 + 16 + fr][fk];
    }
    if constexpr (WLO) {
      blr[0] = *(v8h*)&Bl[wx * 32 + fr][fk];
      blr[1] = *(v8h*)&Bl[wx * 32 + 16 + fr][fk];
    }
#pragma unroll
    for (int mi = 0; mi < 2; ++mi)
#pragma unroll
      for (int ni = 0; ni < 2; ++ni) {
        acc[mi][ni] = __builtin_amdgcn_mfma_f32_16x16x32_f16(ah[mi], bh[ni], acc[mi][ni], 0, 0, 0);
        if constexpr (ALO)
          acc[mi][ni] = __builtin_amdgcn_mfma_f32_16x16x32_f16(alr[mi], bh[ni], acc[mi][ni], 0, 0, 0);
        if constexpr (WLO)
          acc[mi][ni] = __builtin_amdgcn_mfma_f32_16x16x32_f16(ah[mi], blr[ni], acc[mi][ni], 0, 0, 0);
      }
    __syncthreads();
  }
  const int fr = lane & 15, fq = lane >> 4;
#pragma unroll
  for (int mi = 0; mi < 2; ++mi)
#pragma unroll
    for (int ni = 0; ni < 2; ++ni)
#pragma unroll
      for (int j = 0; j < 4; ++j) {
        int row = m0 + wy * 32 + mi * 16 + fq * 4 + j;
        int col = n0 + wx * 32 + ni * 16 + fr;
        float v = acc[mi][ni][j];
        if (BIAS) v += bias[bz * sB + col];
        if (C32)
          ((float*)Cp)[bz * sC + (long)row * N + col] = v;
        else
          ((_Float16*)Cp)[bz * sC + (long)row * N + col] = (_Float16)v;
      }
}

// ---------------- recurrent GRU layer: 8-wave (512thr), AGPR/LDS weight-resident ----------------
// Wave ww owns TWO 16x16 output tiles: cols [w*64+(hp*2+u)*16, +16), w=ww&3,
// hp=ww>>2, u in {0,1}. r,z weights for both tiles -> 128 AGPRs.
// n-gate is 128KB total (256 cols x 256 k x 2B) -> does NOT fit LDS whole
// (rounds 10/11 staged 128KB into a 64KB array, smashing hb+gib -> absmax 650).
// Split like round 8: ht-tiles 0..2 (96KB) in LDS; ht=3 tile in 32 VGPRs (wn3).
// LDS total = 96 + 8 + 48 = 152KB (round 8 launched at exactly this size).
__global__ __launch_bounds__(512, 2) void gru_layer_k(const _Float16* __restrict__ gi,   // (2,T,768) fp16, bih included
                                                      const _Float16* __restrict__ Whh,  // (2,768,256) fp16
                                                      const float* __restrict__ bhh,     // (2,768)
                                                      _Float16* __restrict__ y,          // (T,512) fp16
                                                      float* __restrict__ hfinal) {      // (2,256,256) fp32
  __shared__ _Float16 wlds[49152];      // 96KB: n-gate ht<3, [kch(32)][wq(4)][ht(3)][c16(16)]x8
  __shared__ _Float16 hb[4096];         // 8KB: h fp16, [kc][fq][row][8]
  __shared__ _Float16 gib[2][12288];    // 48KB: gi tile double buffer (16 rows x 768)
  const int dir = blockIdx.y;
  const int r0 = blockIdx.x * 16;
  const int tid = threadIdx.x, lane = tid & 63, ww = tid >> 6;
  const int fr = lane & 15, fq = lane >> 4;
  const int w = ww & 3, hp = ww >> 2;  // hp in [0,2): this wave's ht = hp*2+u
  const _Float16* Wd = Whh + (long)dir * 768 * 256;
  const _Float16* gid = gi + (long)dir * T_ * 768;

  // stage n-gate ht-tiles 0..2 into LDS: i = ((kch*4 + wq)*3 + ht)*16 + c16
  for (int i = tid; i < 6144; i += 512) {
    int c16 = i & 15;
    int r = i >> 4;
    int ht = r % 3; r /= 3;
    int wq = r & 3;
    int kch = r >> 2;
    int col = wq * 64 + ht * 16 + c16;
    *(v8h*)&wlds[(size_t)i * 8] = *(const v8h*)(Wd + (long)(512 + col) * 256 + kch * 8);
  }
  for (int i = tid; i < 2048; i += 512) ((int*)hb)[i] = 0;

  // r,z weights for both tiles -> AGPR-destined i4 (128 AGPRs);
  // n-gate ht=3 tile -> VGPR (used by hp=1,u=1 waves; uniform load keeps code simple)
  i4 wr[2][8], wz[2][8];
  v8h wn3[8];
  int colu[2];
  float bhr[2], bhz[2], bhn[2];
#pragma unroll
  for (int u = 0; u < 2; ++u) {
    const int col = w * 64 + (hp * 2 + u) * 16 + fr;
    colu[u] = col;
#pragma unroll
    for (int kc = 0; kc < 8; ++kc) {
      wr[u][kc] = *(const i4*)(Wd + (long)col * 256 + kc * 32 + fq * 8);
      wz[u][kc] = *(const i4*)(Wd + (long)(256 + col) * 256 + kc * 32 + fq * 8);
    }
    bhr[u] = bhh[(long)dir * 768 + col];
    bhz[u] = bhh[(long)dir * 768 + 256 + col];
    bhn[u] = bhh[(long)dir * 768 + 512 + col];
  }
#pragma unroll
  for (int kc = 0; kc < 8; ++kc)
    wn3[kc] = *(const v8h*)(Wd + (long)(512 + w * 64 + 48 + fr) * 256 + kc * 32 + fq * 8);

  float hreg[2][4];
#pragma unroll
  for (int u = 0; u < 2; ++u)
#pragma unroll
    for (int j = 0; j < 4; ++j) hreg[u][j] = 0.f;

  // prefetch gi tile for the first step (24KB = 3 chunks x 512thr x 16B)
  {
    const _Float16* gb = gid + ((long)(dir ? 63 : 0) * 256 + r0) * 768;
#pragma unroll
    for (int c = 0; c < 3; ++c)
      async_cp16(gb + c * 4096 + tid * 8, &gib[0][c * 4096 + tid * 8]);
  }
  __syncthreads();  // full drain: weights + hb staged, first tile landed

  const v4f z4 = {0.f, 0.f, 0.f, 0.f};
  int cur = 0;
  for (int step = 0; step < 64; ++step) {
    const int t = dir ? 63 - step : step;
    // read h fragments (prev step): a[kc] = h[row=fr][k=kc*32+fq*8+0..7]
    v8h a[8];
#pragma unroll
    for (int kc = 0; kc < 8; ++kc)
      a[kc] = *(const v8h*)&hb[((kc * 4 + fq) * 16 + fr) * 8];
    // prefetch next step's gi tile (stays in flight across the raw barrier)
    if (step < 63) {
      const _Float16* gb = gid + ((long)(dir ? 62 - step : step + 1) * 256 + r0) * 768;
#pragma unroll
      for (int c = 0; c < 3; ++c)
        async_cp16(gb + c * 4096 + tid * 8, &gib[cur ^ 1][c * 4096 + tid * 8]);
    }
    bar_lgkm();  // h reads retired; waves synced; prefetch still outstanding

#pragma unroll
    for (int u = 0; u < 2; ++u) {
      const int ht = hp * 2 + u;
      const int col = colu[u];
      v4f cr = z4, cz = z4, cn = z4;
#pragma unroll
      for (int kc = 0; kc < 8; ++kc) {
        cr = mfma_ag(a[kc], wr[u][kc], cr);
        cz = mfma_ag(a[kc], wz[u][kc], cz);
        v8h w2;
        if (ht < 3)
          w2 = *(const v8h*)&wlds[((((kc * 4 + fq) * 4 + w) * 3 + ht) * 16 + fr) * 8];
        else
          w2 = wn3[kc];
        cn = __builtin_amdgcn_mfma_f32_16x16x32_f16(a[kc], w2, cn, 0, 0, 0);
      }
      cr = mfma_fence(cr);  // dataflow nop fence for the asm MFMAs
      cz = mfma_fence(cz);

      const _Float16* gl = &gib[cur][(fq * 4) * 768 + col];
#pragma unroll
      for (int j = 0; j < 4; ++j) {
        float gr = (float)gl[j * 768];
        float gz = (float)gl[j * 768 + 256];
        float gn = (float)gl[j * 768 + 512];
        float rr = sigm(gr + cr[j] + bhr[u]);
        float zz = sigm(gz + cz[j] + bhz[u]);
        float nn = tanh_f(gn + rr * (cn[j] + bhn[u]));
        float hnew = (1.f - zz) * nn + zz * hreg[u][j];
        hreg[u][j] = hnew;
        y[((long)t * 256 + r0 + fq * 4 + j) * 512 + (long)dir * 256 + col] = (_Float16)hnew;
        hb[(((col >> 5) * 4 + ((col >> 3) & 3)) * 16 + (fq * 4 + j)) * 8 + (col & 7)] = (_Float16)hnew;
      }
    }
    bar_step_end();  // hb writes visible; prefetch (oldest vmem) completed
    cur ^= 1;
  }
#pragma unroll
  for (int u = 0; u < 2; ++u)
#pragma unroll
    for (int j = 0; j < 4; ++j)
      hfinal[((long)dir * 256 + r0 + fq * 4 + j) * 256 + colu[u]] = hreg[u][j];
}

// ---------------- seq-major -> node-major permutation (fp16 rows of 512) ----------------
__global__ __launch_bounds__(256) void permgather_k(const _Float16* __restrict__ inp, _Float16* __restrict__ nb) {
  int t = blockIdx.x, tid = threadIdx.x;
  const unsigned* s = (const unsigned*)(inp + ((long)(t & 63) * 256 + (t >> 6)) * 512);
  unsigned* d = (unsigned*)(nb + (long)t * 512);
  d[tid] = s[tid];
}

// ---------------- CSR aggregation: agg[v] = sum_{e: dst=v} P[src[e]] + pe[et[e]] ----------------
__global__ __launch_bounds__(256) void aggregate_k(const int* __restrict__ rowptr,
                                                   const int* __restrict__ eord,
                                                   const int* __restrict__ src,
                                                   const int* __restrict__ et,
                                                   const float* __restrict__ P,
                                                   const float* __restrict__ pe,
                                                   float* __restrict__ agg) {
  int v = blockIdx.x * 4 + (threadIdx.x >> 6);
  int lane = threadIdx.x & 63;
  int b0 = rowptr[v], b1 = rowptr[v + 1];
  v4f acc = {0.f, 0.f, 0.f, 0.f};
  for (int i = b0; i < b1; ++i) {
    int e = eord[i];
    int s = src[e], ty = et[e];
    v4f pv = *(const v4f*)(P + (long)s * 256 + lane * 4);
    v4f ev = *(const v4f*)(pe + ty * 256 + lane * 4);
    acc += pv + ev;
  }
  *(v4f*)(agg + (long)v * 256 + lane * 4) = acc;
}

// ---------------- GRU cell elementwise (biases already in gi2/gh2) ----------------
__global__ __launch_bounds__(256) void cell_ew_k(const float* __restrict__ gi2,
                                                 const float* __restrict__ gh2,
                                                 float* __restrict__ nodeh) {
  int node = blockIdx.x, j = threadIdx.x;
  const float* a = gi2 + (long)node * 768;
  const float* b = gh2 + (long)node * 768;
  float rr = sigm(a[j] + b[j]);
  float zz = sigm(a[j + 256] + b[j + 256]);
  float nn = tanh_f(a[j + 512] + rr * b[j + 512]);
  float h = nodeh[(long)node * 256 + j];
  nodeh[(long)node * 256 + j] = (1.f - zz) * nn + zz * h;
}

// ---------------- gated sum per graph (fp32 pre-activations) ----------------
__global__ __launch_bounds__(256) void graph_reduce_k(const float* __restrict__ gt,
                                                      const float* __restrict__ bgate,
                                                      const float* __restrict__ bemb,
                                                      float* __restrict__ ge) {
  int g = blockIdx.x, tid = threadIdx.x;
  for (int col = tid; col < 512; col += 256) {
    float bg = bgate[col], be = bemb[col];
    float acc = 0.f;
    for (int p = 0; p < 64; ++p) {
      const float* row = gt + ((long)g * 64 + p) * 1024;
      acc += sigm(row[col] + bg) * (row[512 + col] + be);
    }
    ge[(long)g * 512 + col] = acc;
  }
}

// ---------------- merged = [hf|hb|graph_emb] @ Wglob^T + bglob (fp32) ----------------
__global__ __launch_bounds__(256) void merged_k(const float* __restrict__ hfinal,
                                                const float* __restrict__ ge,
                                                const float* __restrict__ Wglob,
                                                const float* __restrict__ bglob,
                                                float* __restrict__ out) {
  __shared__ float vec[1024];
  int g = blockIdx.x, tid = threadIdx.x;
  vec[tid] = hfinal[(long)g * 256 + tid];
  vec[256 + tid] = hfinal[(long)65536 + g * 256 + tid];
  vec[512 + tid] = ge[(long)g * 512 + tid];
  vec[768 + tid] = ge[(long)g * 512 + 256 + tid];
  __syncthreads();
  const float* wr = Wglob + (long)tid * 1024;
  float acc = bglob[tid];
  for (int k = 0; k < 1024; ++k) acc += vec[k] * wr[k];
  out[(long)g * 256 + tid] = acc;
}

// =========================== host ===========================
extern "C" void kernel_launch(void* const* d_in, const int* in_sizes, int n_in,
                              void* d_out, int out_size, void* d_ws, size_t ws_size,
                              hipStream_t stream) {
  (void)in_sizes; (void)n_in; (void)out_size; (void)ws_size;
  const float* node_table = (const float*)d_in[0];
  const float* Wih_l0 = (const float*)d_in[1];
  const float* Wih_l12 = (const float*)d_in[2];
  const float* WhhF = (const float*)d_in[3];
  const float* bih = (const float*)d_in[4];
  const float* bhh = (const float*)d_in[5];
  const float* WmdF = (const float*)d_in[6];
  const float* bmd = (const float*)d_in[7];
  const float* edge_table = (const float*)d_in[8];
  const float* Wmsg = (const float*)d_in[9];
  const float* bmsg = (const float*)d_in[10];
  const float* cWih = (const float*)d_in[11];
  const float* cWhh = (const float*)d_in[12];
  const float* cbih = (const float*)d_in[13];
  const float* cbhh = (const float*)d_in[14];
  const float* Wgate = (const float*)d_in[15];
  const float* bgate = (const float*)d_in[16];
  const float* Wemb = (const float*)d_in[17];
  const float* bemb = (const float*)d_in[18];
  const float* Wglob = (const float*)d_in[19];
  const float* bglob = (const float*)d_in[20];
  const int* node_types = (const int*)d_in[21];
  const int* edge_types = (const int*)d_in[22];
  const int* srcI = (const int*)d_in[23];
  const int* dstI = (const int*)d_in[24];

  float* node_h = (float*)d_out;                  // (T,256) = output 0, used as working buffer
  float* merged = (float*)d_out + (long)T_ * 256; // (256,256) = output 1

  char* w = (char*)d_ws;
  size_t off = 0;
  auto alloc = [&](size_t bytes) -> char* {
    char* ptr = w + off;
    off = (off + bytes + 255) & ~(size_t)255;
    return ptr;
  };
  _Float16* wWih0H = (_Float16*)alloc((size_t)2 * 768 * 256 * 2);
  _Float16* wWih0L = (_Float16*)alloc((size_t)2 * 768 * 256 * 2);
  _Float16* wWih12H = (_Float16*)alloc((size_t)2 * 2 * 768 * 512 * 2);
  _Float16* wWih12L = (_Float16*)alloc((size_t)2 * 2 * 768 * 512 * 2);
  _Float16* wWhh = (_Float16*)alloc((size_t)3 * 2 * 768 * 256 * 2);
  _Float16* wWmdH = (_Float16*)alloc((size_t)256 * 512 * 2);
  _Float16* wWmdL = (_Float16*)alloc((size_t)256 * 512 * 2);
  _Float16* wWxH = (_Float16*)alloc((size_t)256 * 256 * 2);
  _Float16* wWxL = (_Float16*)alloc((size_t)256 * 256 * 2);
  _Float16* wCWihH = (_Float16*)alloc((size_t)768 * 256 * 2);
  _Float16* wCWihL = (_Float16*)alloc((size_t)768 * 256 * 2);
  _Float16* wCWhhH = (_Float16*)alloc((size_t)768 * 256 * 2);
  _Float16* wCWhhL = (_Float16*)alloc((size_t)768 * 256 * 2);
  _Float16* wWcatH = (_Float16*)alloc((size_t)1024 * 256 * 2);
  _Float16* wWcatL = (_Float16*)alloc((size_t)1024 * 256 * 2);
  _Float16* inpA = (_Float16*)alloc((size_t)T_ * 512 * 2);
  _Float16* inpB = (_Float16*)alloc((size_t)T_ * 512 * 2);
  float* agg = (float*)alloc((size_t)T_ * 256 * 4);
  float* hfinal = (float*)alloc((size_t)2 * 256 * 256 * 4);
  float* pe = (float*)alloc((size_t)16 * 256 * 4);
  int* cnt = (int*)alloc((size_t)T_ * 4);
  int* rowptr = (int*)alloc((size_t)(T_ + 1) * 4);
  int* cur = (int*)alloc((size_t)T_ * 4);
  int* eord = (int*)alloc((size_t)E_ * 4);
  float* gemb = (float*)alloc((size_t)256 * 512 * 4);
  // Union region, 112 MB: phases do not overlap in time.
  //   GRU phase:  gi (2,T,768) fp16 = 48 MB @ +0 ; x0 (T,256) fp16 = 8 MB @ +96M
  //   MP phase:   Pbuf (T,256) = 16 MB @ +0 ; gi2 (T,768) = 48 MB @ +16M ; gh2 @ +64M
  //   epilogue:   gated (T,1024) fp32 = 64 MB @ +0
  char* R = alloc((size_t)112 * 1024 * 1024);
  _Float16* gi = (_Float16*)R;
  _Float16* x0 = (_Float16*)(R + (size_t)96 * 1024 * 1024);
  float* Pbuf = (float*)R;
  float* gi2 = (float*)(R + (size_t)16 * 1024 * 1024);
  float* gh2 = (float*)(R + (size_t)64 * 1024 * 1024);
  float* gatedF = (float*)R;

  // 1. weights -> fp16 hi (+ lo residual where W-systematic error matters downstream)
  CJobs jobs;
  jobs.j[0] = {Wih_l0, wWih0H, wWih0L, 2 * 768 * 256, 2 * 768 * 256, 2 * 768 * 256};
  jobs.j[1] = {Wih_l12, wWih12H, wWih12L, 2 * 2 * 768 * 512, 2 * 2 * 768 * 512, 2 * 2 * 768 * 512};
  jobs.j[2] = {WhhF, wWhh, nullptr, 3 * 2 * 768 * 256, 3 * 2 * 768 * 256, 3 * 2 * 768 * 256};
  jobs.j[3] = {WmdF, wWmdH, wWmdL, 256 * 512, 256 * 512, 256 * 512};
  jobs.j[4] = {Wmsg, wWxH, wWxL, 256 * 256, 256, 512};  // W_x = Wmsg[:, :256]
  jobs.j[5] = {cWih, wCWihH, wCWihL, 768 * 256, 768 * 256, 768 * 256};
  jobs.j[6] = {cWhh, wCWhhH, wCWhhL, 768 * 256, 768 * 256, 768 * 256};
  jobs.j[7] = {Wgate, wWcatH, wWcatL, 512 * 256, 512 * 256, 512 * 256};
  jobs.j[8] = {Wemb, wWcatH + 512 * 256, wWcatL + 512 * 256, 512 * 256, 512 * 256, 512 * 256};
  convert_k<<<1024, 256, 0, stream>>>(jobs);

  // 2. embeddings, edge-type bias, CSR
  embed_k<<<T_, 256, 0, stream>>>(node_types, node_table, x0);
  pe_k<<<1, 256, 0, stream>>>(edge_table, Wmsg, bmsg, pe);
  hipMemsetAsync(cnt, 0, (size_t)T_ * 4, stream);
  count_k<<<E_ / 256, 256, 0, stream>>>(dstI, cnt);
  csr_scan_k<<<1, 256, 0, stream>>>(cnt, rowptr, cur);
  fill_k<<<E_ / 256, 256, 0, stream>>>(dstI, cur, eord);

  // 3. three bidirectional GRU layers (gi fp16 2-term GEMM; 8-wave resident recurrence)
  const _Float16* inCur = x0;
  _Float16* outBuf[3] = {inpA, inpB, inpA};
  int Kin = 256;
  for (int l = 0; l < 3; ++l) {
    const _Float16 *WlH, *WlL;
    long sW;
    if (l == 0) { WlH = wWih0H; WlL = wWih0L; sW = (long)768 * 256; }
    else {
      WlH = wWih12H + (size_t)(l - 1) * 2 * 768 * 512;
      WlL = wWih12L + (size_t)(l - 1) * 2 * 768 * 512;
      sW = (long)768 * 512;
    }
    gemm_nt<1, 0, 1, 0, 1><<<dim3(T_ / 64, 12, 2), 256, 0, stream>>>(
        inCur, WlH, WlL, bih + (long)l * 2 * 768, gi, T_, 768, Kin, 0L, sW, 768L, (long)T_ * 768);
    gru_layer_k<<<dim3(16, 2), 512, 0, stream>>>(
        gi, wWhh + (size_t)l * 2 * 768 * 256, bhh + (long)l * 2 * 768, outBuf[l], hfinal);
    inCur = outBuf[l];
    Kin = 512;
  }

  // 4. permute seq-major -> node-major; node_h = node_bidir @ Wmd^T + bmd
  permgather_k<<<T_, 256, 0, stream>>>(inpA, inpB);
  gemm_nt<1, 0, 1, 1, 1><<<dim3(T_ / 64, 4, 1), 256, 0, stream>>>(
      inpB, wWmdH, wWmdL, bmd, node_h, T_, 256, 512, 0L, 0L, 0L, 0L);

  // 5. message passing x3 (2-term GEMMs: a_hi*w_hi + a_hi*w_lo; W-systematic error killed)
  for (int it = 0; it < 3; ++it) {
    gemm_nt<0, 0, 1, 1, 0><<<dim3(T_ / 64, 4, 1), 256, 0, stream>>>(
        node_h, wWxH, wWxL, nullptr, Pbuf, T_, 256, 256, 0L, 0L, 0L, 0L);
    aggregate_k<<<T_ / 4, 256, 0, stream>>>(rowptr, eord, srcI, edge_types, Pbuf, pe, agg);
    gemm_nt<0, 0, 1, 1, 1><<<dim3(T_ / 64, 12, 1), 256, 0, stream>>>(
        agg, wCWihH, wCWihL, cbih, gi2, T_, 768, 256, 0L, 0L, 0L, 0L);
    gemm_nt<0, 0, 1, 1, 1><<<dim3(T_ / 64, 12, 1), 256, 0, stream>>>(
        node_h, wCWhhH, wCWhhL, cbhh, gh2, T_, 768, 256, 0L, 0L, 0L, 0L);
    cell_ew_k<<<T_, 256, 0, stream>>>(gi2, gh2, node_h);
  }

  // 6. gated projections (2-term, fp32 out) + per-graph sum + merged
  gemm_nt<0, 0, 1, 1, 0><<<dim3(T_ / 64, 16, 1), 256, 0, stream>>>(
      node_h, wWcatH, wWcatL, nullptr, gatedF, T_, 1024, 256, 0L, 0L, 0L, 0L);
  graph_reduce_k<<<256, 256, 0, stream>>>(gatedF, bgate, bemb, gemb);
  merged_k<<<256, 256, 0, stream>>>(hfinal, gemb, Wglob, bglob, merged);
}

// Round 15
// 1378.202 us; speedup vs baseline: 2.4954x; 1.0740x over previous
//
#include <hip/hip_runtime.h>

typedef __attribute__((ext_vector_type(8))) _Float16 v8h;
typedef __attribute__((ext_vector_type(4))) float v4f;
typedef __attribute__((ext_vector_type(4))) int i4;

#define DEV __device__ __forceinline__

constexpr int S_ = 64;
constexpr int B_ = 256;
constexpr int E_ = 131072;
constexpr int T_ = S_ * B_;   // 16384

DEV float sigm(float x) { return 1.f / (1.f + __expf(-x)); }
DEV float tanh_f(float x) { return 1.f - 2.f / (__expf(2.f * x) + 1.f); }

// MFMA with B operand pinned to AGPRs ("a" constraint) — keeps step-invariant
// weights in the AGPR file without touching the VGPR budget.
DEV v4f mfma_ag(v8h a, i4 w, v4f c) {
  asm volatile("v_mfma_f32_16x16x32_f16 %0, %1, %2, %0" : "+v"(c) : "v"(a), "a"(w));
  return c;
}
// Dataflow hazard fence: accumulator threaded THROUGH the nops -> consumers
// ordered after MFMA writes by data dependence (round 6 lesson).
DEV v4f mfma_fence(v4f c) {
  asm volatile("s_nop 7\n\ts_nop 7" : "+v"(c));
  return c;
}
// Async global->LDS copy, 16B per lane (linear LDS dest = base + lane*16).
DEV void async_cp16(const _Float16* g, _Float16* l) {
  __builtin_amdgcn_global_load_lds(
      (const __attribute__((address_space(1))) void*)g,
      (__attribute__((address_space(3))) void*)l, 16, 0, 0);
}
// Raw barrier + counted waits (memory clobber pins loads/stores on their side).
DEV void bar_lgkm() {
  asm volatile("s_waitcnt lgkmcnt(0)" ::: "memory");
  __builtin_amdgcn_s_barrier();
}
DEV void bar_step_end() {
  // per wave/step: the 3 prefetch global_load_lds are issued BEFORE the 8
  // y-stores, so waiting to <=8 outstanding retires all prefetches (and any
  // older stores). y-stores may stay in flight (nobody reads y here).
  asm volatile("s_waitcnt vmcnt(8) lgkmcnt(0)" ::: "memory");
  __builtin_amdgcn_s_barrier();
}

// ---------------- weight fp32 -> fp16 (hi, optional lo residual) ----------------
struct CJob { const float* s; _Float16* d; _Float16* dlo; int n; int rowLen; int stride; };
struct CJobs { CJob j[9]; };

__global__ __launch_bounds__(256) void convert_k(CJobs jobs) {
  for (int q = 0; q < 9; ++q) {
    CJob jb = jobs.j[q];
    for (int i = blockIdx.x * 256 + threadIdx.x; i < jb.n; i += gridDim.x * 256) {
      int row = i / jb.rowLen;
      int col = i - row * jb.rowLen;
      float f = jb.s[(long)row * jb.stride + col];
      _Float16 hi = (_Float16)f;
      jb.d[i] = hi;
      if (jb.dlo) jb.dlo[i] = (_Float16)(f - (float)hi);
    }
  }
}

// ---------------- node embedding gather (fp32 table -> fp16) ----------------
__global__ __launch_bounds__(256) void embed_k(const int* __restrict__ nt,
                                               const float* __restrict__ tab,
                                               _Float16* __restrict__ x0) {
  int t = blockIdx.x, j = threadIdx.x;
  x0[(long)t * 256 + j] = (_Float16)tab[nt[t] * 256 + j];
}

// ---------------- per-edge-type bias: pe[16][256] = edge_table @ W_e^T + bmsg (fp32 exact) ----------------
__global__ __launch_bounds__(256) void pe_k(const float* __restrict__ etab,
                                            const float* __restrict__ Wmsg,
                                            const float* __restrict__ bmsg,
                                            float* __restrict__ pe) {
  int j = threadIdx.x;
  const float* w = Wmsg + (long)j * 512 + 256;  // W_e = Wmsg[:, 256:512]
  for (int r = 0; r < 16; ++r) {
    float acc = bmsg[j];
    const float* e = etab + r * 256;
    for (int k = 0; k < 256; ++k) acc += e[k] * w[k];
    pe[r * 256 + j] = acc;
  }
}

// ---------------- CSR build (by dst) ----------------
__global__ __launch_bounds__(256) void count_k(const int* __restrict__ dst, int* __restrict__ cnt) {
  int e = blockIdx.x * 256 + threadIdx.x;
  if (e < E_) atomicAdd(&cnt[dst[e]], 1);
}

__global__ __launch_bounds__(256) void csr_scan_k(const int* __restrict__ cnt,
                                                  int* __restrict__ rowptr,
                                                  int* __restrict__ cur) {
  __shared__ int ps[256];
  int tid = threadIdx.x;
  int base = tid * 64;
  int s = 0;
  for (int i = 0; i < 64; ++i) s += cnt[base + i];
  ps[tid] = s;
  __syncthreads();
  for (int d = 1; d < 256; d <<= 1) {
    int v = (tid >= d) ? ps[tid - d] : 0;
    __syncthreads();
    ps[tid] += v;
    __syncthreads();
  }
  int run = (tid == 0) ? 0 : ps[tid - 1];
  for (int i = 0; i < 64; ++i) {
    rowptr[base + i] = run;
    cur[base + i] = run;
    run += cnt[base + i];
  }
  if (tid == 255) rowptr[T_] = run;
}

__global__ __launch_bounds__(256) void fill_k(const int* __restrict__ dst,
                                              int* __restrict__ cur,
                                              int* __restrict__ eord) {
  int e = blockIdx.x * 256 + threadIdx.x;
  if (e < E_) {
    int p = atomicAdd(&cur[dst[e]], 1);
    eord[p] = e;
  }
}

// ---------------- 128x128-tile MFMA GEMM: C[M,N] = A[M,K] @ W[N,K]^T (+bias) ----------------
// AH=1: A fp16 plain; AH=0: A fp32 converted to fp16 hi on the fly.
// W always hi+lo (2-term). Validated numerically == gemm_nt (rounds 13/14
// produced bit-identical outputs with/without it). 4 waves 2x2, 64x64/wave.
template <int AH, int C32, int BIAS>
__global__ __launch_bounds__(256, 2) void gemm128(const void* __restrict__ Ap,
                                                  const _Float16* __restrict__ Wp,
                                                  const _Float16* __restrict__ Wlp,
                                                  const float* __restrict__ bias,
                                                  void* __restrict__ Cp,
                                                  int M, int N, int K,
                                                  long sA, long sW, long sB, long sC) {
  __shared__ _Float16 As[128][40];
  __shared__ _Float16 Bs[128][40];
  __shared__ _Float16 Bl[128][40];
  const int bz = blockIdx.z;
  const int m0 = blockIdx.x * 128, n0 = blockIdx.y * 128;
  const int tid = threadIdx.x, lane = tid & 63, ww = tid >> 6;
  const int wy = ww >> 1, wx = ww & 1;
  const int fr = lane & 15, fq = lane >> 4, fk = fq * 8;
  const int sr = tid >> 1, sc = (tid & 1) * 16;
  const _Float16* W = Wp + bz * sW;
  const _Float16* Wl = Wlp + bz * sW;
  v4f acc[4][4];
#pragma unroll
  for (int a = 0; a < 4; ++a)
#pragma unroll
    for (int b = 0; b < 4; ++b) acc[a][b] = (v4f){0.f, 0.f, 0.f, 0.f};

  for (int k0 = 0; k0 < K; k0 += 32) {
    if constexpr (AH) {
      const _Float16* A = (const _Float16*)Ap + bz * sA;
      const _Float16* p = A + (long)(m0 + sr) * K + k0 + sc;
      *(v8h*)&As[sr][sc] = *(const v8h*)p;
      *(v8h*)&As[sr][sc + 8] = *(const v8h*)(p + 8);
    } else {
      const float* A = (const float*)Ap + bz * sA;
      const float* p = A + (long)(m0 + sr) * K + k0 + sc;
      v4f f0 = *(const v4f*)p, f1 = *(const v4f*)(p + 4);
      v4f f2 = *(const v4f*)(p + 8), f3 = *(const v4f*)(p + 12);
      v8h h0, h1;
#pragma unroll
      for (int j = 0; j < 4; ++j) {
        h0[j] = (_Float16)f0[j]; h0[4 + j] = (_Float16)f1[j];
        h1[j] = (_Float16)f2[j]; h1[4 + j] = (_Float16)f3[j];
      }
      *(v8h*)&As[sr][sc] = h0;
      *(v8h*)&As[sr][sc + 8] = h1;
    }
    {
      const _Float16* p = W + (long)(n0 + sr) * K + k0 + sc;
      *(v8h*)&Bs[sr][sc] = *(const v8h*)p;
      *(v8h*)&Bs[sr][sc + 8] = *(const v8h*)(p + 8);
      const _Float16* q = Wl + (long)(n0 + sr) * K + k0 + sc;
      *(v8h*)&Bl[sr][sc] = *(const v8h*)q;
      *(v8h*)&Bl[sr][sc + 8] = *(const v8h*)(q + 8);
    }
    __syncthreads();
    v8h av[4], bh[4], blr[4];
#pragma unroll
    for (int mi = 0; mi < 4; ++mi) av[mi] = *(v8h*)&As[wy * 64 + mi * 16 + fr][fk];
#pragma unroll
    for (int ni = 0; ni < 4; ++ni) {
      bh[ni] = *(v8h*)&Bs[wx * 64 + ni * 16 + fr][fk];
      blr[ni] = *(v8h*)&Bl[wx * 64 + ni * 16 + fr][fk];
    }
#pragma unroll
    for (int mi = 0; mi < 4; ++mi)
#pragma unroll
      for (int ni = 0; ni < 4; ++ni) {
        acc[mi][ni] = __builtin_amdgcn_mfma_f32_16x16x32_f16(av[mi], bh[ni], acc[mi][ni], 0, 0, 0);
        acc[mi][ni] = __builtin_amdgcn_mfma_f32_16x16x32_f16(av[mi], blr[ni], acc[mi][ni], 0, 0, 0);
      }
    __syncthreads();
  }
#pragma unroll
  for (int mi = 0; mi < 4; ++mi)
#pragma unroll
    for (int ni = 0; ni < 4; ++ni)
#pragma unroll
      for (int j = 0; j < 4; ++j) {
        int row = m0 + wy * 64 + mi * 16 + fq * 4 + j;
        int col = n0 + wx * 64 + ni * 16 + fr;
        float v = acc[mi][ni][j];
        if (BIAS) v += bias[bz * sB + col];
        if (C32)
          ((float*)Cp)[bz * sC + (long)row * N + col] = v;
        else
          ((_Float16*)Cp)[bz * sC + (long)row * N + col] = (_Float16)v;
      }
}

// ---------------- recurrent GRU layer: 8-wave (512thr), AGPR/LDS weight-resident ----------------
// EXACT round-12 passing kernel (wlds layout v1). The v2 "conflict-free"
// relayout failed twice with identical error signatures (rounds 13/14) despite
// a verified-bijective mapping — reverted; the 1.05M bank conflicts are an
// accepted ~10% cost on this kernel.
__global__ __launch_bounds__(512, 2) void gru_layer_k(const _Float16* __restrict__ gi,   // (2,T,768) fp16, bih included
                                                      const _Float16* __restrict__ Whh,  // (2,768,256) fp16
                                                      const float* __restrict__ bhh,     // (2,768)
                                                      _Float16* __restrict__ y,          // (T,512) fp16
                                                      float* __restrict__ hfinal) {      // (2,256,256) fp32
  __shared__ _Float16 wlds[49152];      // 96KB: n-gate ht<3, [kch][wq][ht][c16]x8
  __shared__ _Float16 hb[4096];         // 8KB: h fp16, contiguous per kc
  __shared__ _Float16 gib[2][12288];    // 48KB: gi tile double buffer (16 rows x 768)
  const int dir = blockIdx.y;
  const int r0 = blockIdx.x * 16;
  const int tid = threadIdx.x, lane = tid & 63, ww = tid >> 6;
  const int fr = lane & 15, fq = lane >> 4;
  const int w = ww & 3, hp = ww >> 2;  // hp in [0,2): this wave's ht = hp*2+u
  const _Float16* Wd = Whh + (long)dir * 768 * 256;
  const _Float16* gid = gi + (long)dir * T_ * 768;

  // stage n-gate ht-tiles 0..2 into LDS: i = ((kch*4 + wq)*3 + ht)*16 + c16
  for (int i = tid; i < 6144; i += 512) {
    int c16 = i & 15;
    int r = i >> 4;
    int ht = r % 3; r /= 3;
    int wq = r & 3;
    int kch = r >> 2;
    int col = wq * 64 + ht * 16 + c16;
    *(v8h*)&wlds[(size_t)i * 8] = *(const v8h*)(Wd + (long)(512 + col) * 256 + kch * 8);
  }
  for (int i = tid; i < 2048; i += 512) ((int*)hb)[i] = 0;

  // r,z weights for both tiles -> AGPR-destined i4 (128 AGPRs);
  // n-gate ht=3 tile -> VGPR (used by hp=1,u=1 waves; uniform load keeps code simple)
  i4 wr[2][8], wz[2][8];
  v8h wn3[8];
  int colu[2];
  float bhr[2], bhz[2], bhn[2];
#pragma unroll
  for (int u = 0; u < 2; ++u) {
    const int col = w * 64 + (hp * 2 + u) * 16 + fr;
    colu[u] = col;
#pragma unroll
    for (int kc = 0; kc < 8; ++kc) {
      wr[u][kc] = *(const i4*)(Wd + (long)col * 256 + kc * 32 + fq * 8);
      wz[u][kc] = *(const i4*)(Wd + (long)(256 + col) * 256 + kc * 32 + fq * 8);
    }
    bhr[u] = bhh[(long)dir * 768 + col];
    bhz[u] = bhh[(long)dir * 768 + 256 + col];
    bhn[u] = bhh[(long)dir * 768 + 512 + col];
  }
#pragma unroll
  for (int kc = 0; kc < 8; ++kc)
    wn3[kc] = *(const v8h*)(Wd + (long)(512 + w * 64 + 48 + fr) * 256 + kc * 32 + fq * 8);

  float hreg[2][4];
#pragma unroll
  for (int u = 0; u < 2; ++u)
#pragma unroll
    for (int j = 0; j < 4; ++j) hreg[u][j] = 0.f;

  // prefetch gi tile for the first step (24KB = 3 chunks x 512thr x 16B)
  {
    const _Float16* gb = gid + ((long)(dir ? 63 : 0) * 256 + r0) * 768;
#pragma unroll
    for (int c = 0; c < 3; ++c)
      async_cp16(gb + c * 4096 + tid * 8, &gib[0][c * 4096 + tid * 8]);
  }
  __syncthreads();  // full drain: weights + hb staged, first tile landed

  const v4f z4 = {0.f, 0.f, 0.f, 0.f};
  int cur = 0;
  for (int step = 0; step < 64; ++step) {
    const int t = dir ? 63 - step : step;
    // read h fragments (prev step): a[kc] = h[row=fr][k=kc*32+fq*8+0..7]
    v8h a[8];
#pragma unroll
    for (int kc = 0; kc < 8; ++kc)
      a[kc] = *(const v8h*)&hb[((kc * 4 + fq) * 16 + fr) * 8];
    // prefetch next step's gi tile (stays in flight across the raw barrier)
    if (step < 63) {
      const _Float16* gb = gid + ((long)(dir ? 62 - step : step + 1) * 256 + r0) * 768;
#pragma unroll
      for (int c = 0; c < 3; ++c)
        async_cp16(gb + c * 4096 + tid * 8, &gib[cur ^ 1][c * 4096 + tid * 8]);
    }
    bar_lgkm();  // h reads retired; waves synced; prefetch still outstanding

#pragma unroll
    for (int u = 0; u < 2; ++u) {
      const int ht = hp * 2 + u;
      const int col = colu[u];
      v4f cr = z4, cz = z4, cn = z4;
#pragma unroll
      for (int kc = 0; kc < 8; ++kc) {
        cr = mfma_ag(a[kc], wr[u][kc], cr);
        cz = mfma_ag(a[kc], wz[u][kc], cz);
        v8h w2;
        if (ht < 3)
          w2 = *(const v8h*)&wlds[((((kc * 4 + fq) * 4 + w) * 3 + ht) * 16 + fr) * 8];
        else
          w2 = wn3[kc];
        cn = __builtin_amdgcn_mfma_f32_16x16x32_f16(a[kc], w2, cn, 0, 0, 0);
      }
      cr = mfma_fence(cr);  // dataflow nop fence for the asm MFMAs
      cz = mfma_fence(cz);

      const _Float16* gl = &gib[cur][(fq * 4) * 768 + col];
#pragma unroll
      for (int j = 0; j < 4; ++j) {
        float gr = (float)gl[j * 768];
        float gz = (float)gl[j * 768 + 256];
        float gn = (float)gl[j * 768 + 512];
        float rr = sigm(gr + cr[j] + bhr[u]);
        float zz = sigm(gz + cz[j] + bhz[u]);
        float nn = tanh_f(gn + rr * (cn[j] + bhn[u]));
        float hnew = (1.f - zz) * nn + zz * hreg[u][j];
        hreg[u][j] = hnew;
        y[((long)t * 256 + r0 + fq * 4 + j) * 512 + (long)dir * 256 + col] = (_Float16)hnew;
        hb[(((col >> 5) * 4 + ((col >> 3) & 3)) * 16 + (fq * 4 + j)) * 8 + (col & 7)] = (_Float16)hnew;
      }
    }
    bar_step_end();  // hb writes visible; prefetch (oldest vmem) completed
    cur ^= 1;
  }
#pragma unroll
  for (int u = 0; u < 2; ++u)
#pragma unroll
    for (int j = 0; j < 4; ++j)
      hfinal[((long)dir * 256 + r0 + fq * 4 + j) * 256 + colu[u]] = hreg[u][j];
}

// ---------------- seq-major -> node-major permutation (fp16 rows of 512) ----------------
__global__ __launch_bounds__(256) void permgather_k(const _Float16* __restrict__ inp, _Float16* __restrict__ nb) {
  int t = blockIdx.x, tid = threadIdx.x;
  const unsigned* s = (const unsigned*)(inp + ((long)(t & 63) * 256 + (t >> 6)) * 512);
  unsigned* d = (unsigned*)(nb + (long)t * 512);
  d[tid] = s[tid];
}

// ---------------- CSR aggregation: agg[v] = sum_{e: dst=v} P[src[e]] + pe[et[e]] ----------------
__global__ __launch_bounds__(256) void aggregate_k(const int* __restrict__ rowptr,
                                                   const int* __restrict__ eord,
                                                   const int* __restrict__ src,
                                                   const int* __restrict__ et,
                                                   const float* __restrict__ P,
                                                   const float* __restrict__ pe,
                                                   float* __restrict__ agg) {
  int v = blockIdx.x * 4 + (threadIdx.x >> 6);
  int lane = threadIdx.x & 63;
  int b0 = rowptr[v], b1 = rowptr[v + 1];
  v4f acc = {0.f, 0.f, 0.f, 0.f};
  for (int i = b0; i < b1; ++i) {
    int e = eord[i];
    int s = src[e], ty = et[e];
    v4f pv = *(const v4f*)(P + (long)s * 256 + lane * 4);
    v4f ev = *(const v4f*)(pe + ty * 256 + lane * 4);
    acc += pv + ev;
  }
  *(v4f*)(agg + (long)v * 256 + lane * 4) = acc;
}

// ---------------- GRU cell elementwise (biases already in gi2/gh2) ----------------
__global__ __launch_bounds__(256) void cell_ew_k(const float* __restrict__ gi2,
                                                 const float* __restrict__ gh2,
                                                 float* __restrict__ nodeh) {
  int node = blockIdx.x, j = threadIdx.x;
  const float* a = gi2 + (long)node * 768;
  const float* b = gh2 + (long)node * 768;
  float rr = sigm(a[j] + b[j]);
  float zz = sigm(a[j + 256] + b[j + 256]);
  float nn = tanh_f(a[j + 512] + rr * b[j + 512]);
  float h = nodeh[(long)node * 256 + j];
  nodeh[(long)node * 256 + j] = (1.f - zz) * nn + zz * h;
}

// ---------------- gated sum per graph (fp32 pre-activations) ----------------
__global__ __launch_bounds__(256) void graph_reduce_k(const float* __restrict__ gt,
                                                      const float* __restrict__ bgate,
                                                      const float* __restrict__ bemb,
                                                      float* __restrict__ ge) {
  int g = blockIdx.x, tid = threadIdx.x;
  for (int col = tid; col < 512; col += 256) {
    float bg = bgate[col], be = bemb[col];
    float acc = 0.f;
    for (int p = 0; p < 64; ++p) {
      const float* row = gt + ((long)g * 64 + p) * 1024;
      acc += sigm(row[col] + bg) * (row[512 + col] + be);
    }
    ge[(long)g * 512 + col] = acc;
  }
}

// ---------------- merged = [hf|hb|graph_emb] @ Wglob^T + bglob (fp32) ----------------
__global__ __launch_bounds__(256) void merged_k(const float* __restrict__ hfinal,
                                                const float* __restrict__ ge,
                                                const float* __restrict__ Wglob,
                                                const float* __restrict__ bglob,
                                                float* __restrict__ out) {
  __shared__ float vec[1024];
  int g = blockIdx.x, tid = threadIdx.x;
  vec[tid] = hfinal[(long)g * 256 + tid];
  vec[256 + tid] = hfinal[(long)65536 + g * 256 + tid];
  vec[512 + tid] = ge[(long)g * 512 + tid];
  vec[768 + tid] = ge[(long)g * 512 + 256 + tid];
  __syncthreads();
  const float* wr = Wglob + (long)tid * 1024;
  float acc = bglob[tid];
  for (int k = 0; k < 1024; ++k) acc += vec[k] * wr[k];
  out[(long)g * 256 + tid] = acc;
}

// =========================== host ===========================
extern "C" void kernel_launch(void* const* d_in, const int* in_sizes, int n_in,
                              void* d_out, int out_size, void* d_ws, size_t ws_size,
                              hipStream_t stream) {
  (void)in_sizes; (void)n_in; (void)out_size; (void)ws_size;
  const float* node_table = (const float*)d_in[0];
  const float* Wih_l0 = (const float*)d_in[1];
  const float* Wih_l12 = (const float*)d_in[2];
  const float* WhhF = (const float*)d_in[3];
  const float* bih = (const float*)d_in[4];
  const float* bhh = (const float*)d_in[5];
  const float* WmdF = (const float*)d_in[6];
  const float* bmd = (const float*)d_in[7];
  const float* edge_table = (const float*)d_in[8];
  const float* Wmsg = (const float*)d_in[9];
  const float* bmsg = (const float*)d_in[10];
  const float* cWih = (const float*)d_in[11];
  const float* cWhh = (const float*)d_in[12];
  const float* cbih = (const float*)d_in[13];
  const float* cbhh = (const float*)d_in[14];
  const float* Wgate = (const float*)d_in[15];
  const float* bgate = (const float*)d_in[16];
  const float* Wemb = (const float*)d_in[17];
  const float* bemb = (const float*)d_in[18];
  const float* Wglob = (const float*)d_in[19];
  const float* bglob = (const float*)d_in[20];
  const int* node_types = (const int*)d_in[21];
  const int* edge_types = (const int*)d_in[22];
  const int* srcI = (const int*)d_in[23];
  const int* dstI = (const int*)d_in[24];

  float* node_h = (float*)d_out;                  // (T,256) = output 0, used as working buffer
  float* merged = (float*)d_out + (long)T_ * 256; // (256,256) = output 1

  char* w = (char*)d_ws;
  size_t off = 0;
  auto alloc = [&](size_t bytes) -> char* {
    char* ptr = w + off;
    off = (off + bytes + 255) & ~(size_t)255;
    return ptr;
  };
  _Float16* wWih0H = (_Float16*)alloc((size_t)2 * 768 * 256 * 2);
  _Float16* wWih0L = (_Float16*)alloc((size_t)2 * 768 * 256 * 2);
  _Float16* wWih12H = (_Float16*)alloc((size_t)2 * 2 * 768 * 512 * 2);
  _Float16* wWih12L = (_Float16*)alloc((size_t)2 * 2 * 768 * 512 * 2);
  _Float16* wWhh = (_Float16*)alloc((size_t)3 * 2 * 768 * 256 * 2);
  _Float16* wWmdH = (_Float16*)alloc((size_t)256 * 512 * 2);
  _Float16* wWmdL = (_Float16*)alloc((size_t)256 * 512 * 2);
  _Float16* wWxH = (_Float16*)alloc((size_t)256 * 256 * 2);
  _Float16* wWxL = (_Float16*)alloc((size_t)256 * 256 * 2);
  _Float16* wCWihH = (_Float16*)alloc((size_t)768 * 256 * 2);
  _Float16* wCWihL = (_Float16*)alloc((size_t)768 * 256 * 2);
  _Float16* wCWhhH = (_Float16*)alloc((size_t)768 * 256 * 2);
  _Float16* wCWhhL = (_Float16*)alloc((size_t)768 * 256 * 2);
  _Float16* wWcatH = (_Float16*)alloc((size_t)1024 * 256 * 2);
  _Float16* wWcatL = (_Float16*)alloc((size_t)1024 * 256 * 2);
  _Float16* inpA = (_Float16*)alloc((size_t)T_ * 512 * 2);
  _Float16* inpB = (_Float16*)alloc((size_t)T_ * 512 * 2);
  float* agg = (float*)alloc((size_t)T_ * 256 * 4);
  float* hfinal = (float*)alloc((size_t)2 * 256 * 256 * 4);
  float* pe = (float*)alloc((size_t)16 * 256 * 4);
  int* cnt = (int*)alloc((size_t)T_ * 4);
  int* rowptr = (int*)alloc((size_t)(T_ + 1) * 4);
  int* cur = (int*)alloc((size_t)T_ * 4);
  int* eord = (int*)alloc((size_t)E_ * 4);
  float* gemb = (float*)alloc((size_t)256 * 512 * 4);
  // Union region, 112 MB: phases do not overlap in time.
  //   GRU phase:  gi (2,T,768) fp16 = 48 MB @ +0 ; x0 (T,256) fp16 = 8 MB @ +96M
  //   MP phase:   Pbuf (T,256) = 16 MB @ +0 ; gi2 (T,768) = 48 MB @ +16M ; gh2 @ +64M
  //   epilogue:   gated (T,1024) fp32 = 64 MB @ +0
  char* R = alloc((size_t)112 * 1024 * 1024);
  _Float16* gi = (_Float16*)R;
  _Float16* x0 = (_Float16*)(R + (size_t)96 * 1024 * 1024);
  float* Pbuf = (float*)R;
  float* gi2 = (float*)(R + (size_t)16 * 1024 * 1024);
  float* gh2 = (float*)(R + (size_t)64 * 1024 * 1024);
  float* gatedF = (float*)R;

  // 1. weights -> fp16 hi (+ lo residual where W-systematic error matters downstream)
  CJobs jobs;
  jobs.j[0] = {Wih_l0, wWih0H, wWih0L, 2 * 768 * 256, 2 * 768 * 256, 2 * 768 * 256};
  jobs.j[1] = {Wih_l12, wWih12H, wWih12L, 2 * 2 * 768 * 512, 2 * 2 * 768 * 512, 2 * 2 * 768 * 512};
  jobs.j[2] = {WhhF, wWhh, nullptr, 3 * 2 * 768 * 256, 3 * 2 * 768 * 256, 3 * 2 * 768 * 256};
  jobs.j[3] = {WmdF, wWmdH, wWmdL, 256 * 512, 256 * 512, 256 * 512};
  jobs.j[4] = {Wmsg, wWxH, wWxL, 256 * 256, 256, 512};  // W_x = Wmsg[:, :256]
  jobs.j[5] = {cWih, wCWihH, wCWihL, 768 * 256, 768 * 256, 768 * 256};
  jobs.j[6] = {cWhh, wCWhhH, wCWhhL, 768 * 256, 768 * 256, 768 * 256};
  jobs.j[7] = {Wgate, wWcatH, wWcatL, 512 * 256, 512 * 256, 512 * 256};
  jobs.j[8] = {Wemb, wWcatH + 512 * 256, wWcatL + 512 * 256, 512 * 256, 512 * 256, 512 * 256};
  convert_k<<<1024, 256, 0, stream>>>(jobs);

  // 2. embeddings, edge-type bias, CSR
  embed_k<<<T_, 256, 0, stream>>>(node_types, node_table, x0);
  pe_k<<<1, 256, 0, stream>>>(edge_table, Wmsg, bmsg, pe);
  hipMemsetAsync(cnt, 0, (size_t)T_ * 4, stream);
  count_k<<<E_ / 256, 256, 0, stream>>>(dstI, cnt);
  csr_scan_k<<<1, 256, 0, stream>>>(cnt, rowptr, cur);
  fill_k<<<E_ / 256, 256, 0, stream>>>(dstI, cur, eord);

  // 3. three bidirectional GRU layers (gi fp16 2-term 128^2 GEMM; 8-wave resident recurrence)
  const _Float16* inCur = x0;
  _Float16* outBuf[3] = {inpA, inpB, inpA};
  int Kin = 256;
  for (int l = 0; l < 3; ++l) {
    const _Float16 *WlH, *WlL;
    long sW;
    if (l == 0) { WlH = wWih0H; WlL = wWih0L; sW = (long)768 * 256; }
    else {
      WlH = wWih12H + (size_t)(l - 1) * 2 * 768 * 512;
      WlL = wWih12L + (size_t)(l - 1) * 2 * 768 * 512;
      sW = (long)768 * 512;
    }
    gemm128<1, 0, 1><<<dim3(T_ / 128, 6, 2), 256, 0, stream>>>(
        inCur, WlH, WlL, bih + (long)l * 2 * 768, gi, T_, 768, Kin, 0L, sW, 768L, (long)T_ * 768);
    gru_layer_k<<<dim3(16, 2), 512, 0, stream>>>(
        gi, wWhh + (size_t)l * 2 * 768 * 256, bhh + (long)l * 2 * 768, outBuf[l], hfinal);
    inCur = outBuf[l];
    Kin = 512;
  }

  // 4. permute seq-major -> node-major; node_h = node_bidir @ Wmd^T + bmd
  permgather_k<<<T_, 256, 0, stream>>>(inpA, inpB);
  gemm128<1, 1, 1><<<dim3(T_ / 128, 2, 1), 256, 0, stream>>>(
      inpB, wWmdH, wWmdL, bmd, node_h, T_, 256, 512, 0L, 0L, 0L, 0L);

  // 5. message passing x3 (2-term 128^2 GEMMs)
  for (int it = 0; it < 3; ++it) {
    gemm128<0, 1, 0><<<dim3(T_ / 128, 2, 1), 256, 0, stream>>>(
        node_h, wWxH, wWxL, nullptr, Pbuf, T_, 256, 256, 0L, 0L, 0L, 0L);
    aggregate_k<<<T_ / 4, 256, 0, stream>>>(rowptr, eord, srcI, edge_types, Pbuf, pe, agg);
    gemm128<0, 1, 1><<<dim3(T_ / 128, 6, 1), 256, 0, stream>>>(
        agg, wCWihH, wCWihL, cbih, gi2, T_, 768, 256, 0L, 0L, 0L, 0L);
    gemm128<0, 1, 1><<<dim3(T_ / 128, 6, 1), 256, 0, stream>>>(
        node_h, wCWhhH, wCWhhL, cbhh, gh2, T_, 768, 256, 0L, 0L, 0L, 0L);
    cell_ew_k<<<T_, 256, 0, stream>>>(gi2, gh2, node_h);
  }

  // 6. gated projections (2-term, fp32 out) + per-graph sum + merged
  gemm128<0, 1, 0><<<dim3(T_ / 128, 8, 1), 256, 0, stream>>>(
      node_h, wWcatH, wWcatL, nullptr, gatedF, T_, 1024, 256, 0L, 0L, 0L, 0L);
  graph_reduce_k<<<256, 256, 0, stream>>>(gatedF, bgate, bemb, gemb);
  merged_k<<<256, 256, 0, stream>>>(hfinal, gemb, Wglob, bglob, merged);
}